// Round 10
// baseline (241.220 us; speedup 1.0000x reference)
//
#include <hip/hip_runtime.h>

#define B_ 64
#define CIN 64
#define T_ 2048
#define C1 16
#define T1 1024
#define C2 32
#define T2 512
#define NN 32768
#define HID 256
#define OUTD 10
#define NE 524288
#define NTOT (NE + NN)          // 557056

typedef __attribute__((ext_vector_type(4))) float fx4;
typedef __attribute__((ext_vector_type(8))) _Float16 hx8;
typedef __attribute__((ext_vector_type(4))) _Float16 hx4;
typedef __attribute__((ext_vector_type(2))) _Float16 hx2;

// ---- workspace byte offsets (ends ~51.5 MB; ws proven >= 75 MB) ----
#define OFF_H      (0ull)                    // 16 MB: H fp16 [N][256]
#define OFF_Z      (16ull<<20)               // 16 MB + 64K: Z fp16 [N+1][256] (row NN = zero dummy)
#define OFF_H1     (33ull<<20)               // 4 MB: conv1 out
#define OFF_XN     (37ull<<20)               // 2 MB + 64B: xn fp16 [N+1][32] (row NN = zero dummy)
#define OFF_Y1     (42ull<<20)               // 4 MB: agg1 out fp32 [N][32]
#define OFF_DEG    (46ull<<20)               // 128 KB int
#define OFF_INDPTR ((46ull<<20) + (256u<<10))
#define OFF_CNT    ((46ull<<20) + (512u<<10))
#define OFF_DINV   ((46ull<<20) + (768u<<10))   // [N+1] floats
#define OFF_CSRC   (47ull<<20)               // padded CSR src, cap 3.25 MB
#define OFF_WT1    (51ull<<20)               // 20 KB
#define OFF_WT2    (OFF_WT1 + (64u<<10))
#define OFF_POOL   (OFF_WT1 + (128u<<10))
#define OFF_W2T    (OFF_WT1 + (256u<<10))    // 128 KB: W2^T fp16

__device__ __forceinline__ fx4 shfl_xor4(fx4 v, int m) {
    return (fx4){__shfl_xor(v.x, m), __shfl_xor(v.y, m), __shfl_xor(v.z, m), __shfl_xor(v.w, m)};
}

// setup: blocks 0..127 init deg/cnt/pooled (+zero dummy rows of xn, Z);
// 128..143 cvtw (W2->W2T fp16); 144..173 twt (conv weight transpose)
__global__ __launch_bounds__(256) void k_setup(int* deg, int* cnt, float* pooled,
                                               const float* __restrict__ w1, const float* __restrict__ w2,
                                               float* __restrict__ wt1, float* __restrict__ wt2,
                                               const float* __restrict__ gw2, _Float16* __restrict__ w2t,
                                               unsigned* __restrict__ xnz, unsigned* __restrict__ zz) {
    __shared__ float tl[64][65];
    int blk = blockIdx.x, t = threadIdx.x;
    if (blk < 128) {
        int i = blk * 256 + t;
        if (i < NN) { deg[i] = 1; cnt[i] = 0; }   // deg starts at 1 (self-loop)
        if (i < B_ * HID) pooled[i] = 0.f;
        if (blk == 0 && t < 16) xnz[t] = 0u;      // xn dummy row NN (64 B fp16)
        if (blk == 1 && t < 128) zz[t] = 0u;      // Z dummy row NN (512 B)
    } else if (blk < 144) {
        int bb = blk - 128;
        int bx = bb & 3, by = bb >> 2;            // k-tile, n-tile
        #pragma unroll
        for (int it = 0; it < 16; it++) {
            int idx = it * 256 + t;
            int r = idx >> 6, c = idx & 63;
            tl[r][c] = gw2[(size_t)(bx * 64 + r) * 256 + by * 64 + c];
        }
        __syncthreads();
        #pragma unroll
        for (int it = 0; it < 16; it++) {
            int idx = it * 256 + t;
            int r = idx >> 6, c = idx & 63;
            w2t[(size_t)(by * 64 + r) * 256 + bx * 64 + c] = (_Float16)tl[c][r];
        }
    } else {
        int i = (blk - 144) * 256 + t;
        if (i < 16 * 64 * 5) {
            int co = i & 15; int r = i >> 4; int k = r % 5; int ci = r / 5;
            wt1[i] = w1[(co * 64 + ci) * 5 + k];
        }
        int j = i - 16 * 64 * 5;
        if (j >= 0 && j < 32 * 16 * 5) {
            int co = j & 31; int r = j >> 5; int k = r % 5; int ci = r / 5;
            wt2[j] = w2[(co * 16 + ci) * 5 + k];
        }
    }
}

// count: 4 edges per thread (int4), 512 blocks
__global__ __launch_bounds__(256) void k_count(const int* __restrict__ ei, int* __restrict__ deg) {
    int t = blockIdx.x * 256 + threadIdx.x;   // < NE/4
    int4 d4 = *(const int4*)&ei[NE + 4 * t];
    atomicAdd(&deg[d4.x], 1);
    atomicAdd(&deg[d4.y], 1);
    atomicAdd(&deg[d4.z], 1);
    atomicAdd(&deg[d4.w], 1);
}

// scan over PADDED degrees ((deg+7)&~7); emits dinv = rsqrt(real deg), dinv[NN]=0.
__global__ __launch_bounds__(1024) void k_scan(const int* __restrict__ deg, int* __restrict__ indptr,
                                               float* __restrict__ dinv) {
    __shared__ int wsum[16];
    int tid = threadIdx.x;
    int lane = tid & 63, w = tid >> 6;
    int base = tid * 32;
    int loc[32]; int s = 0;
    #pragma unroll
    for (int j = 0; j < 32; j++) {
        int d = deg[base + j];
        dinv[base + j] = rsqrtf((float)d);
        loc[j] = d;
        s += (d + 7) & ~7;
    }
    int v = s;                       // inclusive wave scan
    #pragma unroll
    for (int off = 1; off < 64; off <<= 1) {
        int t = __shfl_up(v, off);
        if (lane >= off) v += t;
    }
    if (lane == 63) wsum[w] = v;
    __syncthreads();
    int woff = 0;
    #pragma unroll
    for (int i = 0; i < 16; i++) { int t = wsum[i]; if (i < w) woff += t; }
    int run = woff + v - s;          // exclusive prefix for this thread
    #pragma unroll
    for (int j = 0; j < 32; j++) { indptr[base + j] = run; run += (loc[j] + 7) & ~7; }
    if (tid == 1023) { indptr[NN] = run; dinv[NN] = 0.f; }
}

// fill: threads [0, NE/4): 4 edges each (int4); [NE/4, NE/4+NN): self-loops;
// rest: pad sentinels (src=NN) into slots [deg, degp). 768 blocks.
__global__ __launch_bounds__(256) void k_fill(const int* __restrict__ ei, const int* __restrict__ deg,
                                              const int* __restrict__ indptr, int* __restrict__ cnt,
                                              int* __restrict__ csrc) {
    int t = blockIdx.x * 256 + threadIdx.x;
    if (t < NE / 4) {
        int4 s4 = *(const int4*)&ei[4 * t];
        int4 d4 = *(const int4*)&ei[NE + 4 * t];
        int p0 = indptr[d4.x] + atomicAdd(&cnt[d4.x], 1); csrc[p0] = s4.x;
        int p1 = indptr[d4.y] + atomicAdd(&cnt[d4.y], 1); csrc[p1] = s4.y;
        int p2 = indptr[d4.z] + atomicAdd(&cnt[d4.z], 1); csrc[p2] = s4.z;
        int p3 = indptr[d4.w] + atomicAdd(&cnt[d4.w], 1); csrc[p3] = s4.w;
    } else if (t < NE / 4 + NN) {
        int n = t - NE / 4;
        int pos = indptr[n] + atomicAdd(&cnt[n], 1);
        csrc[pos] = n;
    } else {
        int n = t - NE / 4 - NN;
        if (n < NN) {
            int dd = deg[n], dp = (dd + 7) & ~7, base = indptr[n];
            for (int j = dd; j < dp; j++) csrc[base + j] = NN;
        }
    }
}

// conv1: x[64,64,2048] -> relu -> pool2 -> h1[64,16,1024]; single-phase staging
__global__ __launch_bounds__(256) void k_conv1(const float* __restrict__ x, const float* __restrict__ wt1,
                                               const float* __restrict__ b1, float* __restrict__ h1) {
    __shared__ float xs[64][260];
    __shared__ float ps[16][128];
    int tid = threadIdx.x;
    int tile = blockIdx.x;      // 0..7, 256 t each
    int b = blockIdx.y;
    int t0 = tile * 256;
    const float* xb = x + ((size_t)b * CIN) * T_ + t0;
    {   // interior cols 0..255 -> xs[r][2..257], 16 fx4 per thread
        int f = tid & 63, r0 = tid >> 6;
        #pragma unroll
        for (int it = 0; it < 16; it++) {
            int r = r0 + 4 * it;
            fx4 v = *(const fx4*)&xb[(size_t)r * T_ + f * 4];
            *(fx4*)&xs[r][2 + f * 4] = v;
        }
        // halo cols {-2,-1,256,257} -> xs[r][{0,1,258,259}], 1 per thread
        int r = tid >> 2, c = tid & 3;
        int off = (c < 2) ? (c - 2) : (254 + c);
        int gt = t0 + off;
        float v = 0.f;
        if (gt >= 0 && gt < T_) v = xb[(size_t)r * T_ + off];
        xs[r][2 + off] = v;
    }
    __syncthreads();
    float acc[16];
    #pragma unroll
    for (int i = 0; i < 16; i++) acc[i] = 0.f;
    #pragma unroll 4
    for (int ci = 0; ci < 64; ci++) {
        float xv[5];
        #pragma unroll
        for (int j = 0; j < 5; j++) xv[j] = xs[ci][tid + j];
        const float* wp = wt1 + ci * 80;
        #pragma unroll
        for (int k = 0; k < 5; k++) {
            #pragma unroll
            for (int co = 0; co < 16; co++)
                acc[co] = fmaf(xv[k], wp[k * 16 + co], acc[co]);
        }
    }
    #pragma unroll
    for (int co = 0; co < 16; co++) {
        float a = fmaxf(acc[co] + b1[co], 0.f);
        float o = fmaxf(a, __shfl_xor(a, 1));
        if ((tid & 1) == 0) ps[co][tid >> 1] = o;
    }
    __syncthreads();
    for (int idx = tid; idx < 16 * 128; idx += 256) {
        int co = idx >> 7; int p = idx & 127;
        h1[(b * C1 + co) * T1 + tile * 128 + p] = ps[co][p];
    }
}

// conv2: h1[64,16,1024] -> relu -> pool2 -> xn fp16 [N,32] (node-major)
__global__ __launch_bounds__(256) void k_conv2(const float* __restrict__ h1, const float* __restrict__ wt2,
                                               const float* __restrict__ b2, _Float16* __restrict__ xn) {
    __shared__ float xs[16][260];
    __shared__ float ps[128 * 32];
    int tid = threadIdx.x;
    int tile = blockIdx.x;      // 0..3
    int b = blockIdx.y;
    int t0 = tile * 256;
    float acc[32];
    #pragma unroll
    for (int i = 0; i < 32; i++) acc[i] = 0.f;
    for (int idx = tid; idx < 16 * 260; idx += 256) {
        int r = idx / 260, c = idx % 260;
        int gt = t0 + c - 2;
        float v = 0.f;
        if (gt >= 0 && gt < T1) v = h1[(b * C1 + r) * T1 + gt];
        xs[r][c] = v;
    }
    __syncthreads();
    for (int ci = 0; ci < 16; ci++) {
        float xv[5];
        #pragma unroll
        for (int j = 0; j < 5; j++) xv[j] = xs[ci][tid + j];
        const float* wp = wt2 + (ci * 5) * 32;
        #pragma unroll
        for (int k = 0; k < 5; k++) {
            #pragma unroll
            for (int co = 0; co < 32; co++)
                acc[co] = fmaf(xv[k], wp[k * 32 + co], acc[co]);
        }
    }
    #pragma unroll
    for (int co = 0; co < 32; co++) {
        float a = fmaxf(acc[co] + b2[co], 0.f);
        float o = fmaxf(a, __shfl_xor(a, 1));
        if ((tid & 1) == 0) ps[(tid >> 1) * 32 + co] = o;
    }
    __syncthreads();
    size_t base = ((size_t)b * T2 + tile * 128) * 32;
    for (int idx = tid; idx < 128 * 16; idx += 256) {
        hx2 h;
        h.x = (_Float16)ps[2 * idx];
        h.y = (_Float16)ps[2 * idx + 1];
        *(hx2*)&xn[base + 2 * idx] = h;
    }
}

#define ACC4(v, m) \
    acc.x = fmaf((float)v[0], m, acc.x); acc.y = fmaf((float)v[1], m, acc.y); \
    acc.z = fmaf((float)v[2], m, acc.z); acc.w = fmaf((float)v[3], m, acc.w);

// agg1: y1[n,:] = sum_e dinv[s]*dinv[n] * xn[s,:]; xn fp16 (2 MB -> L2-resident
// on every XCD). Wave per node: 8 edge-slots x 8 lanes x hx4, shfl reduce.
__global__ __launch_bounds__(256) void k_agg32(const _Float16* __restrict__ xn, const int* __restrict__ indptr,
                                               const int* __restrict__ csrc, const float* __restrict__ dinv,
                                               float* __restrict__ y1) {
    int lane = threadIdx.x & 63;
    int n = blockIdx.x * 4 + (threadIdx.x >> 6);
    int eg = lane >> 3, fi = lane & 7;
    int beg = indptr[n];
    int cnt8 = indptr[n + 1] - beg;     // multiple of 8
    float dn = dinv[n];
    const int* cs = csrc + beg;
    fx4 acc = (fx4){0.f, 0.f, 0.f, 0.f};
    for (int i = 0; i < cnt8; i += 8) {
        int s = cs[i + eg];
        float m = dinv[s] * dn;
        hx4 v = *(const hx4*)&xn[(size_t)s * 32 + fi * 4];
        ACC4(v, m)
    }
    acc += shfl_xor4(acc, 8);
    acc += shfl_xor4(acc, 16);
    acc += shfl_xor4(acc, 32);
    if (lane < 8) *(fx4*)&y1[(size_t)n * 32 + fi * 4] = acc;
}

// gemm1: H[N,256] = fp16( relu(y1[N,32] @ W1[32,256] + b1) ); 64-row tiles.
__global__ __launch_bounds__(256) void k_gemm1(const float* __restrict__ A, const float* __restrict__ W,
                                               const float* __restrict__ bias, _Float16* __restrict__ H) {
    __shared__ __align__(16) float xT[32 * 68];   // [k][r], 64 rows + pad
    __shared__ __align__(16) float wl[32 * 256];
    int tid = threadIdx.x;
    int ty = tid >> 4, tx = tid & 15;
    int rows0 = blockIdx.x * 64;
    int kq = tid & 7, rs = tid >> 3;              // staging coords (rs 0..31)
    {
        fx4 v0 = *(const fx4*)&A[(size_t)(rows0 + rs) * 32 + kq * 4];
        fx4 v1 = *(const fx4*)&A[(size_t)(rows0 + rs + 32) * 32 + kq * 4];
        #pragma unroll
        for (int i = 0; i < 4; i++) {
            xT[(kq * 4 + i) * 68 + rs]      = v0[i];
            xT[(kq * 4 + i) * 68 + rs + 32] = v1[i];
        }
    }
    #pragma unroll
    for (int m = 0; m < 8; m++)
        *(fx4*)&wl[m * 1024 + tid * 4] = *(const fx4*)&W[(size_t)(m * 1024 + tid * 4)];
    __syncthreads();

    fx4 c[4][4];
    #pragma unroll
    for (int i = 0; i < 4; i++)
        #pragma unroll
        for (int j = 0; j < 4; j++) c[i][j] = (fx4){0.f, 0.f, 0.f, 0.f};

    #pragma unroll 8
    for (int kk = 0; kk < 32; kk++) {
        fx4 xa = *(const fx4*)&xT[kk * 68 + ty * 4];
        fx4 w[4];
        w[0] = *(const fx4*)&wl[kk * 256 + tx * 8];
        w[1] = *(const fx4*)&wl[kk * 256 + tx * 8 + 4];
        w[2] = *(const fx4*)&wl[kk * 256 + tx * 8 + 128];
        w[3] = *(const fx4*)&wl[kk * 256 + tx * 8 + 132];
        #pragma unroll
        for (int j = 0; j < 4; j++) {
            c[0][j] += xa.x * w[j];
            c[1][j] += xa.y * w[j];
            c[2][j] += xa.z * w[j];
            c[3][j] += xa.w * w[j];
        }
    }
    fx4 bb[4];
    bb[0] = *(const fx4*)&bias[tx * 8];
    bb[1] = *(const fx4*)&bias[tx * 8 + 4];
    bb[2] = *(const fx4*)&bias[tx * 8 + 128];
    bb[3] = *(const fx4*)&bias[tx * 8 + 132];
    #pragma unroll
    for (int i = 0; i < 4; i++) {
        int r = rows0 + ty * 4 + i;
        fx4 v0 = c[i][0] + bb[0], v1 = c[i][1] + bb[1];
        fx4 v2 = c[i][2] + bb[2], v3 = c[i][3] + bb[3];
        hx8 h0, h1;
        #pragma unroll
        for (int q = 0; q < 4; q++) {
            h0[q]     = (_Float16)fmaxf(v0[q], 0.f);
            h0[q + 4] = (_Float16)fmaxf(v1[q], 0.f);
            h1[q]     = (_Float16)fmaxf(v2[q], 0.f);
            h1[q + 4] = (_Float16)fmaxf(v3[q], 0.f);
        }
        *(hx8*)&H[(size_t)r * 256 + tx * 8]       = h0;
        *(hx8*)&H[(size_t)r * 256 + tx * 8 + 128] = h1;
    }
}

// gemm2 MFMA: Z[N,256] = fp16( H[N,256] @ W2 ), 128x128 tile, BK=64, dbuf LDS.
#define LDH 72
__global__ __launch_bounds__(256, 2) void k_gemm2m(const _Float16* __restrict__ A,
                                                   const _Float16* __restrict__ Bt,
                                                   _Float16* __restrict__ Z) {
    __shared__ __align__(16) _Float16 As[2][128 * LDH];
    __shared__ __align__(16) _Float16 Bs[2][128 * LDH];
    int tid = threadIdx.x;
    int lane = tid & 63, wid = tid >> 6;
    int wm = wid >> 1, wn = wid & 1;
    int row0 = blockIdx.x * 128, col0 = blockIdx.y * 128;
    int l15 = lane & 15, g = lane >> 4;
    int sr = tid >> 3, sc = tid & 7;

    fx4 acc[4][4];
    #pragma unroll
    for (int m = 0; m < 4; m++)
        #pragma unroll
        for (int n = 0; n < 4; n++) acc[m][n] = (fx4){0.f, 0.f, 0.f, 0.f};

    uint4 ga[4], gb[4];
    #pragma unroll
    for (int it = 0; it < 4; it++) {
        ga[it] = *(const uint4*)&A[(size_t)(row0 + sr + 32 * it) * 256 + sc * 8];
        gb[it] = *(const uint4*)&Bt[(size_t)(col0 + sr + 32 * it) * 256 + sc * 8];
    }
    #pragma unroll
    for (int it = 0; it < 4; it++) {
        *(uint4*)&As[0][(sr + 32 * it) * LDH + sc * 8] = ga[it];
        *(uint4*)&Bs[0][(sr + 32 * it) * LDH + sc * 8] = gb[it];
    }
    __syncthreads();

    int cur = 0;
    for (int t = 0; t < 4; t++) {
        if (t < 3) {
            int k0 = (t + 1) * 64;
            #pragma unroll
            for (int it = 0; it < 4; it++) {
                ga[it] = *(const uint4*)&A[(size_t)(row0 + sr + 32 * it) * 256 + k0 + sc * 8];
                gb[it] = *(const uint4*)&Bt[(size_t)(col0 + sr + 32 * it) * 256 + k0 + sc * 8];
            }
        }
        const _Float16* ap = As[cur];
        const _Float16* bp = Bs[cur];
        hx8 af[4][2], bf[4][2];
        #pragma unroll
        for (int m = 0; m < 4; m++)
            #pragma unroll
            for (int ks = 0; ks < 2; ks++)
                af[m][ks] = *(const hx8*)&ap[(wm * 64 + m * 16 + l15) * LDH + ks * 32 + g * 8];
        #pragma unroll
        for (int n = 0; n < 4; n++)
            #pragma unroll
            for (int ks = 0; ks < 2; ks++)
                bf[n][ks] = *(const hx8*)&bp[(wn * 64 + n * 16 + l15) * LDH + ks * 32 + g * 8];
        #pragma unroll
        for (int m = 0; m < 4; m++)
            #pragma unroll
            for (int n = 0; n < 4; n++) {
                acc[m][n] = __builtin_amdgcn_mfma_f32_16x16x32_f16(af[m][0], bf[n][0], acc[m][n], 0, 0, 0);
                acc[m][n] = __builtin_amdgcn_mfma_f32_16x16x32_f16(af[m][1], bf[n][1], acc[m][n], 0, 0, 0);
            }
        if (t < 3) {
            #pragma unroll
            for (int it = 0; it < 4; it++) {
                *(uint4*)&As[cur ^ 1][(sr + 32 * it) * LDH + sc * 8] = ga[it];
                *(uint4*)&Bs[cur ^ 1][(sr + 32 * it) * LDH + sc * 8] = gb[it];
            }
        }
        __syncthreads();
        cur ^= 1;
    }

    #pragma unroll
    for (int m = 0; m < 4; m++)
        #pragma unroll
        for (int n = 0; n < 4; n++) {
            int cc = col0 + wn * 64 + n * 16 + l15;
            #pragma unroll
            for (int r = 0; r < 4; r++) {
                int rr = row0 + wm * 64 + m * 16 + g * 4 + r;
                Z[(size_t)rr * 256 + cc] = (_Float16)acc[m][n][r];
            }
        }
}

// agg2 + mean, FEATURE-SLICED for XCD-L2 residency: slice = blockIdx&7 (32
// features, 2 MB column-stripe of Z -> fits 4 MB per-XCD L2 under round-robin
// dispatch). Wave: 8 edge-slots x 8 lanes x hx4; 8 nodes sequential; block
// combines 4 waves in LDS; one atomicAdd per feature per block.
__global__ __launch_bounds__(256) void k_aggm(const _Float16* __restrict__ Z, const int* __restrict__ indptr,
                                              const int* __restrict__ csrc, const float* __restrict__ dinv,
                                              const float* __restrict__ bias, float* __restrict__ pooled) {
    __shared__ float ps[4][32];
    int tid = threadIdx.x;
    int wid = tid >> 6, lane = tid & 63;
    int slice = blockIdx.x & 7;          // XCD-affine under round-robin dispatch
    int grp = blockIdx.x >> 3;           // 0..1023 -> 32 nodes each
    int eg = lane >> 3, fi = lane & 7;
    int fbase = slice * 32 + fi * 4;
    fx4 bb = *(const fx4*)&bias[fbase];
    fx4 racc = (fx4){0.f, 0.f, 0.f, 0.f};
    int n0 = grp * 32 + wid * 8;
    #pragma unroll 1
    for (int u = 0; u < 8; u++) {
        int n = n0 + u;
        int beg = indptr[n];
        int cnt8 = indptr[n + 1] - beg;  // multiple of 8 (padded lists)
        float dn = dinv[n];
        const int* cs = csrc + beg;
        fx4 acc = (fx4){0.f, 0.f, 0.f, 0.f};
        for (int i = 0; i < cnt8; i += 8) {
            int s = cs[i + eg];
            float m = dinv[s] * dn;
            hx4 v = *(const hx4*)&Z[(size_t)s * 256 + fbase];
            ACC4(v, m)
        }
        acc += shfl_xor4(acc, 8);
        acc += shfl_xor4(acc, 16);
        acc += shfl_xor4(acc, 32);
        acc += bb;
        racc.x += fmaxf(acc.x, 0.f); racc.y += fmaxf(acc.y, 0.f);
        racc.z += fmaxf(acc.z, 0.f); racc.w += fmaxf(acc.w, 0.f);
    }
    if (eg == 0) *(fx4*)&ps[wid][fi * 4] = racc;
    __syncthreads();
    if (tid < 32) {
        float s = ps[0][tid] + ps[1][tid] + ps[2][tid] + ps[3][tid];
        atomicAdd(&pooled[(grp >> 4) * 256 + slice * 32 + tid], s * (1.f / 512.f));
    }
}

__global__ __launch_bounds__(64) void k_cls(const float* __restrict__ pooled, const float* __restrict__ cw,
                                            const float* __restrict__ cb, float* __restrict__ outp) {
    int b = blockIdx.x, lane = threadIdx.x;
    float po[10];
    #pragma unroll
    for (int o = 0; o < 10; o++) po[o] = 0.f;
    #pragma unroll
    for (int m = 0; m < 4; m++) {
        int hh = lane + m * 64;
        float ph = pooled[b * HID + hh];
        #pragma unroll
        for (int o = 0; o < 10; o++) po[o] = fmaf(ph, cw[hh * 10 + o], po[o]);
    }
    #pragma unroll
    for (int off = 32; off >= 1; off >>= 1) {
        #pragma unroll
        for (int o = 0; o < 10; o++) po[o] += __shfl_down(po[o], off);
    }
    if (lane == 0) {
        #pragma unroll
        for (int o = 0; o < 10; o++) outp[b * 10 + o] = po[o] + cb[o];
    }
}

extern "C" void kernel_launch(void* const* d_in, const int* in_sizes, int n_in,
                              void* d_out, int out_size, void* d_ws, size_t ws_size,
                              hipStream_t stream) {
    const float* x   = (const float*)d_in[0];
    const int*   ei  = (const int*)d_in[1];
    const float* w1  = (const float*)d_in[2];
    const float* b1  = (const float*)d_in[3];
    const float* w2  = (const float*)d_in[4];
    const float* b2  = (const float*)d_in[5];
    const float* g1w = (const float*)d_in[6];
    const float* g1b = (const float*)d_in[7];
    const float* g2w = (const float*)d_in[8];
    const float* g2b = (const float*)d_in[9];
    const float* cw  = (const float*)d_in[10];
    const float* cb  = (const float*)d_in[11];
    float* out = (float*)d_out;
    char* ws = (char*)d_ws;

    _Float16*       H      = (_Float16*)(ws + OFF_H);
    _Float16*       Z      = (_Float16*)(ws + OFF_Z);
    float*          h1     = (float*)(ws + OFF_H1);
    _Float16*       xn     = (_Float16*)(ws + OFF_XN);
    float*          y1     = (float*)(ws + OFF_Y1);
    int*            deg    = (int*)(ws + OFF_DEG);
    int*            indptr = (int*)(ws + OFF_INDPTR);
    int*            cnt    = (int*)(ws + OFF_CNT);
    float*          dinv   = (float*)(ws + OFF_DINV);
    int*            csrc   = (int*)(ws + OFF_CSRC);
    float*          wt1    = (float*)(ws + OFF_WT1);
    float*          wt2    = (float*)(ws + OFF_WT2);
    float*          pooled = (float*)(ws + OFF_POOL);
    _Float16*       w2t    = (_Float16*)(ws + OFF_W2T);
    unsigned*       xnz    = (unsigned*)(xn + (size_t)NN * 32);      // dummy row NN of xn
    unsigned*       zz     = (unsigned*)(Z + (size_t)NN * 256);      // dummy row NN of Z

    k_setup<<<174, 256, 0, stream>>>(deg, cnt, pooled, w1, w2, wt1, wt2, g2w, w2t, xnz, zz);
    k_count<<<512, 256, 0, stream>>>(ei, deg);
    k_conv1<<<dim3(8, 64), 256, 0, stream>>>(x, wt1, b1, h1);
    k_scan <<<1, 1024, 0, stream>>>(deg, indptr, dinv);
    k_fill <<<768, 256, 0, stream>>>(ei, deg, indptr, cnt, csrc);
    k_conv2<<<dim3(4, 64), 256, 0, stream>>>(h1, wt2, b2, xn);
    k_agg32<<<8192, 256, 0, stream>>>(xn, indptr, csrc, dinv, y1);           // y1 = A^ . X (32-wide)
    k_gemm1<<<512, 256, 0, stream>>>(y1, g1w, g1b, H);                       // H = fp16(relu(y1@W1+b1))
    k_gemm2m<<<dim3(256, 2), 256, 0, stream>>>(H, w2t, Z);                   // Z = fp16(H@W2)
    k_aggm <<<8192, 256, 0, stream>>>(Z, indptr, csrc, dinv, g2b, pooled);   // pooled += relu(A^ . Z + b2)/512
    k_cls  <<<64, 64, 0, stream>>>(pooled, cw, cb, out);
}

// Round 11
// 192.178 us; speedup vs baseline: 1.2552x; 1.2552x over previous
//
#include <hip/hip_runtime.h>

#define B_ 64
#define CIN 64
#define T_ 2048
#define C1 16
#define T1 1024
#define C2 32
#define T2 512
#define NN 32768
#define HID 256
#define OUTD 10
#define NE 524288
#define NTOT (NE + NN)          // 557056

typedef __attribute__((ext_vector_type(4))) float fx4;
typedef __attribute__((ext_vector_type(8))) _Float16 hx8;
typedef __attribute__((ext_vector_type(4))) _Float16 hx4;
typedef __attribute__((ext_vector_type(2))) _Float16 hx2;

// ---- workspace byte offsets (ends ~51.5 MB; ws proven >= 75 MB) ----
#define OFF_H      (0ull)                    // 16 MB: H fp16 [N][256]
#define OFF_Z      (16ull<<20)               // 16 MB + 64K: Z fp16 [N+1][256] (row NN = zero dummy)
#define OFF_H1     (33ull<<20)               // 4 MB: conv1 out
#define OFF_XN     (37ull<<20)               // 2 MB + 64B: xn fp16 [N+1][32] (row NN = zero dummy)
#define OFF_Y1     (42ull<<20)               // 4 MB: agg1 out fp32 [N][32]
#define OFF_DEG    (46ull<<20)               // 128 KB int
#define OFF_INDPTR ((46ull<<20) + (256u<<10))
#define OFF_CNT    ((46ull<<20) + (512u<<10))
#define OFF_DINV   ((46ull<<20) + (768u<<10))   // [N+1] floats
#define OFF_CSRC   (47ull<<20)               // padded CSR src, cap 3.25 MB
#define OFF_WT1    (51ull<<20)               // 20 KB
#define OFF_WT2    (OFF_WT1 + (64u<<10))
#define OFF_POOL   (OFF_WT1 + (128u<<10))
#define OFF_W2T    (OFF_WT1 + (256u<<10))    // 128 KB: W2^T fp16

__device__ __forceinline__ fx4 shfl_xor4(fx4 v, int m) {
    return (fx4){__shfl_xor(v.x, m), __shfl_xor(v.y, m), __shfl_xor(v.z, m), __shfl_xor(v.w, m)};
}

// setup: blocks 0..127 init deg/cnt/pooled (+zero dummy rows of xn, Z);
// 128..143 cvtw (W2->W2T fp16); 144..173 twt (conv weight transpose)
__global__ __launch_bounds__(256) void k_setup(int* deg, int* cnt, float* pooled,
                                               const float* __restrict__ w1, const float* __restrict__ w2,
                                               float* __restrict__ wt1, float* __restrict__ wt2,
                                               const float* __restrict__ gw2, _Float16* __restrict__ w2t,
                                               unsigned* __restrict__ xnz, unsigned* __restrict__ zz) {
    __shared__ float tl[64][65];
    int blk = blockIdx.x, t = threadIdx.x;
    if (blk < 128) {
        int i = blk * 256 + t;
        if (i < NN) { deg[i] = 1; cnt[i] = 0; }   // deg starts at 1 (self-loop)
        if (i < B_ * HID) pooled[i] = 0.f;
        if (blk == 0 && t < 16) xnz[t] = 0u;      // xn dummy row NN (64 B fp16)
        if (blk == 1 && t < 128) zz[t] = 0u;      // Z dummy row NN (512 B)
    } else if (blk < 144) {
        int bb = blk - 128;
        int bx = bb & 3, by = bb >> 2;            // k-tile, n-tile
        #pragma unroll
        for (int it = 0; it < 16; it++) {
            int idx = it * 256 + t;
            int r = idx >> 6, c = idx & 63;
            tl[r][c] = gw2[(size_t)(bx * 64 + r) * 256 + by * 64 + c];
        }
        __syncthreads();
        #pragma unroll
        for (int it = 0; it < 16; it++) {
            int idx = it * 256 + t;
            int r = idx >> 6, c = idx & 63;
            w2t[(size_t)(by * 64 + r) * 256 + bx * 64 + c] = (_Float16)tl[c][r];
        }
    } else {
        int i = (blk - 144) * 256 + t;
        if (i < 16 * 64 * 5) {
            int co = i & 15; int r = i >> 4; int k = r % 5; int ci = r / 5;
            wt1[i] = w1[(co * 64 + ci) * 5 + k];
        }
        int j = i - 16 * 64 * 5;
        if (j >= 0 && j < 32 * 16 * 5) {
            int co = j & 31; int r = j >> 5; int k = r % 5; int ci = r / 5;
            wt2[j] = w2[(co * 16 + ci) * 5 + k];
        }
    }
}

// scan over PADDED degrees ((deg+7)&~7); emits dinv = rsqrt(real deg), dinv[NN]=0.
__global__ __launch_bounds__(1024) void k_scan(const int* __restrict__ deg, int* __restrict__ indptr,
                                               float* __restrict__ dinv) {
    __shared__ int wsum[16];
    int tid = threadIdx.x;
    int lane = tid & 63, w = tid >> 6;
    int base = tid * 32;
    int loc[32]; int s = 0;
    #pragma unroll
    for (int j = 0; j < 32; j++) {
        int d = deg[base + j];
        dinv[base + j] = rsqrtf((float)d);
        loc[j] = d;
        s += (d + 7) & ~7;
    }
    int v = s;                       // inclusive wave scan
    #pragma unroll
    for (int off = 1; off < 64; off <<= 1) {
        int t = __shfl_up(v, off);
        if (lane >= off) v += t;
    }
    if (lane == 63) wsum[w] = v;
    __syncthreads();
    int woff = 0;
    #pragma unroll
    for (int i = 0; i < 16; i++) { int t = wsum[i]; if (i < w) woff += t; }
    int run = woff + v - s;          // exclusive prefix for this thread
    #pragma unroll
    for (int j = 0; j < 32; j++) { indptr[base + j] = run; run += (loc[j] + 7) & ~7; }
    if (tid == 1023) { indptr[NN] = run; dinv[NN] = 0.f; }
}

// FUSED conv1 + count. Blocks 0..511: conv1 tile (tile=blk&7, b=blk>>3).
// Blocks 512..1023: degree-count, 4 edges/thread (int4). Independent work —
// the CU scheduler overlaps count's atomic latency under conv1 FMAs.
__global__ __launch_bounds__(256) void k_c1cnt(const float* __restrict__ x, const float* __restrict__ wt1,
                                               const float* __restrict__ b1, float* __restrict__ h1,
                                               const int* __restrict__ ei, int* __restrict__ deg) {
    int blk = blockIdx.x;
    int tid = threadIdx.x;
    if (blk >= 512) {
        int t = (blk - 512) * 256 + tid;   // < NE/4
        int4 d4 = *(const int4*)&ei[NE + 4 * t];
        atomicAdd(&deg[d4.x], 1);
        atomicAdd(&deg[d4.y], 1);
        atomicAdd(&deg[d4.z], 1);
        atomicAdd(&deg[d4.w], 1);
        return;
    }
    __shared__ float xs[64][260];
    __shared__ float ps[16][128];
    int tile = blk & 7;
    int b = blk >> 3;
    int t0 = tile * 256;
    const float* xb = x + ((size_t)b * CIN) * T_ + t0;
    {   // interior cols 0..255 -> xs[r][2..257], 16 fx4 per thread
        int f = tid & 63, r0 = tid >> 6;
        #pragma unroll
        for (int it = 0; it < 16; it++) {
            int r = r0 + 4 * it;
            fx4 v = *(const fx4*)&xb[(size_t)r * T_ + f * 4];
            *(fx4*)&xs[r][2 + f * 4] = v;
        }
        // halo cols {-2,-1,256,257} -> xs[r][{0,1,258,259}], 1 per thread
        int r = tid >> 2, c = tid & 3;
        int off = (c < 2) ? (c - 2) : (254 + c);
        int gt = t0 + off;
        float v = 0.f;
        if (gt >= 0 && gt < T_) v = xb[(size_t)r * T_ + off];
        xs[r][2 + off] = v;
    }
    __syncthreads();
    float acc[16];
    #pragma unroll
    for (int i = 0; i < 16; i++) acc[i] = 0.f;
    #pragma unroll 4
    for (int ci = 0; ci < 64; ci++) {
        float xv[5];
        #pragma unroll
        for (int j = 0; j < 5; j++) xv[j] = xs[ci][tid + j];
        const float* wp = wt1 + ci * 80;
        #pragma unroll
        for (int k = 0; k < 5; k++) {
            #pragma unroll
            for (int co = 0; co < 16; co++)
                acc[co] = fmaf(xv[k], wp[k * 16 + co], acc[co]);
        }
    }
    #pragma unroll
    for (int co = 0; co < 16; co++) {
        float a = fmaxf(acc[co] + b1[co], 0.f);
        float o = fmaxf(a, __shfl_xor(a, 1));
        if ((tid & 1) == 0) ps[co][tid >> 1] = o;
    }
    __syncthreads();
    for (int idx = tid; idx < 16 * 128; idx += 256) {
        int co = idx >> 7; int p = idx & 127;
        h1[(b * C1 + co) * T1 + tile * 128 + p] = ps[co][p];
    }
}

// FUSED conv2 + fill. Blocks 0..255: conv2 (tile=blk&3, b=blk>>2) -> xn fp16.
// Blocks 256..1023: CSR fill (4 edges/thread int4; self-loops; pad sentinels).
__global__ __launch_bounds__(256) void k_c2fill(const float* __restrict__ h1, const float* __restrict__ wt2,
                                                const float* __restrict__ b2, _Float16* __restrict__ xn,
                                                const int* __restrict__ ei, const int* __restrict__ deg,
                                                const int* __restrict__ indptr, int* __restrict__ cnt,
                                                int* __restrict__ csrc) {
    int blk = blockIdx.x;
    int tid = threadIdx.x;
    if (blk >= 256) {
        int t = (blk - 256) * 256 + tid;
        if (t < NE / 4) {
            int4 s4 = *(const int4*)&ei[4 * t];
            int4 d4 = *(const int4*)&ei[NE + 4 * t];
            int p0 = indptr[d4.x] + atomicAdd(&cnt[d4.x], 1); csrc[p0] = s4.x;
            int p1 = indptr[d4.y] + atomicAdd(&cnt[d4.y], 1); csrc[p1] = s4.y;
            int p2 = indptr[d4.z] + atomicAdd(&cnt[d4.z], 1); csrc[p2] = s4.z;
            int p3 = indptr[d4.w] + atomicAdd(&cnt[d4.w], 1); csrc[p3] = s4.w;
        } else if (t < NE / 4 + NN) {
            int n = t - NE / 4;
            int pos = indptr[n] + atomicAdd(&cnt[n], 1);
            csrc[pos] = n;
        } else {
            int n = t - NE / 4 - NN;
            if (n < NN) {
                int dd = deg[n], dp = (dd + 7) & ~7, base = indptr[n];
                for (int j = dd; j < dp; j++) csrc[base + j] = NN;
            }
        }
        return;
    }
    __shared__ float xs[16][260];
    __shared__ float ps[128 * 32];
    int tile = blk & 3;
    int b = blk >> 2;
    int t0 = tile * 256;
    float acc[32];
    #pragma unroll
    for (int i = 0; i < 32; i++) acc[i] = 0.f;
    for (int idx = tid; idx < 16 * 260; idx += 256) {
        int r = idx / 260, c = idx % 260;
        int gt = t0 + c - 2;
        float v = 0.f;
        if (gt >= 0 && gt < T1) v = h1[(b * C1 + r) * T1 + gt];
        xs[r][c] = v;
    }
    __syncthreads();
    for (int ci = 0; ci < 16; ci++) {
        float xv[5];
        #pragma unroll
        for (int j = 0; j < 5; j++) xv[j] = xs[ci][tid + j];
        const float* wp = wt2 + (ci * 5) * 32;
        #pragma unroll
        for (int k = 0; k < 5; k++) {
            #pragma unroll
            for (int co = 0; co < 32; co++)
                acc[co] = fmaf(xv[k], wp[k * 32 + co], acc[co]);
        }
    }
    #pragma unroll
    for (int co = 0; co < 32; co++) {
        float a = fmaxf(acc[co] + b2[co], 0.f);
        float o = fmaxf(a, __shfl_xor(a, 1));
        if ((tid & 1) == 0) ps[(tid >> 1) * 32 + co] = o;
    }
    __syncthreads();
    size_t base = ((size_t)b * T2 + tile * 128) * 32;
    for (int idx = tid; idx < 128 * 16; idx += 256) {
        hx2 h;
        h.x = (_Float16)ps[2 * idx];
        h.y = (_Float16)ps[2 * idx + 1];
        *(hx2*)&xn[base + 2 * idx] = h;
    }
}

#define ACC4(v, m) \
    acc.x = fmaf((float)v[0], m, acc.x); acc.y = fmaf((float)v[1], m, acc.y); \
    acc.z = fmaf((float)v[2], m, acc.z); acc.w = fmaf((float)v[3], m, acc.w);

// agg1: y1[n,:] = sum_e dinv[s]*dinv[n] * xn[s,:]; xn fp16 (2 MB, L2-resident).
// Wave per node: 8 edge-slots x 8 lanes x hx4, shfl reduce.
__global__ __launch_bounds__(256) void k_agg32(const _Float16* __restrict__ xn, const int* __restrict__ indptr,
                                               const int* __restrict__ csrc, const float* __restrict__ dinv,
                                               float* __restrict__ y1) {
    int lane = threadIdx.x & 63;
    int n = blockIdx.x * 4 + (threadIdx.x >> 6);
    int eg = lane >> 3, fi = lane & 7;
    int beg = indptr[n];
    int cnt8 = indptr[n + 1] - beg;     // multiple of 8
    float dn = dinv[n];
    const int* cs = csrc + beg;
    fx4 acc = (fx4){0.f, 0.f, 0.f, 0.f};
    for (int i = 0; i < cnt8; i += 8) {
        int s = cs[i + eg];
        float m = dinv[s] * dn;
        hx4 v = *(const hx4*)&xn[(size_t)s * 32 + fi * 4];
        ACC4(v, m)
    }
    acc += shfl_xor4(acc, 8);
    acc += shfl_xor4(acc, 16);
    acc += shfl_xor4(acc, 32);
    if (lane < 8) *(fx4*)&y1[(size_t)n * 32 + fi * 4] = acc;
}

// gemm1: H[N,256] = fp16( relu(y1[N,32] @ W1[32,256] + b1) ); 64-row tiles.
__global__ __launch_bounds__(256) void k_gemm1(const float* __restrict__ A, const float* __restrict__ W,
                                               const float* __restrict__ bias, _Float16* __restrict__ H) {
    __shared__ __align__(16) float xT[32 * 68];   // [k][r], 64 rows + pad
    __shared__ __align__(16) float wl[32 * 256];
    int tid = threadIdx.x;
    int ty = tid >> 4, tx = tid & 15;
    int rows0 = blockIdx.x * 64;
    int kq = tid & 7, rs = tid >> 3;              // staging coords (rs 0..31)
    {
        fx4 v0 = *(const fx4*)&A[(size_t)(rows0 + rs) * 32 + kq * 4];
        fx4 v1 = *(const fx4*)&A[(size_t)(rows0 + rs + 32) * 32 + kq * 4];
        #pragma unroll
        for (int i = 0; i < 4; i++) {
            xT[(kq * 4 + i) * 68 + rs]      = v0[i];
            xT[(kq * 4 + i) * 68 + rs + 32] = v1[i];
        }
    }
    #pragma unroll
    for (int m = 0; m < 8; m++)
        *(fx4*)&wl[m * 1024 + tid * 4] = *(const fx4*)&W[(size_t)(m * 1024 + tid * 4)];
    __syncthreads();

    fx4 c[4][4];
    #pragma unroll
    for (int i = 0; i < 4; i++)
        #pragma unroll
        for (int j = 0; j < 4; j++) c[i][j] = (fx4){0.f, 0.f, 0.f, 0.f};

    #pragma unroll 8
    for (int kk = 0; kk < 32; kk++) {
        fx4 xa = *(const fx4*)&xT[kk * 68 + ty * 4];
        fx4 w[4];
        w[0] = *(const fx4*)&wl[kk * 256 + tx * 8];
        w[1] = *(const fx4*)&wl[kk * 256 + tx * 8 + 4];
        w[2] = *(const fx4*)&wl[kk * 256 + tx * 8 + 128];
        w[3] = *(const fx4*)&wl[kk * 256 + tx * 8 + 132];
        #pragma unroll
        for (int j = 0; j < 4; j++) {
            c[0][j] += xa.x * w[j];
            c[1][j] += xa.y * w[j];
            c[2][j] += xa.z * w[j];
            c[3][j] += xa.w * w[j];
        }
    }
    fx4 bb[4];
    bb[0] = *(const fx4*)&bias[tx * 8];
    bb[1] = *(const fx4*)&bias[tx * 8 + 4];
    bb[2] = *(const fx4*)&bias[tx * 8 + 128];
    bb[3] = *(const fx4*)&bias[tx * 8 + 132];
    #pragma unroll
    for (int i = 0; i < 4; i++) {
        int r = rows0 + ty * 4 + i;
        fx4 v0 = c[i][0] + bb[0], v1 = c[i][1] + bb[1];
        fx4 v2 = c[i][2] + bb[2], v3 = c[i][3] + bb[3];
        hx8 h0, h1;
        #pragma unroll
        for (int q = 0; q < 4; q++) {
            h0[q]     = (_Float16)fmaxf(v0[q], 0.f);
            h0[q + 4] = (_Float16)fmaxf(v1[q], 0.f);
            h1[q]     = (_Float16)fmaxf(v2[q], 0.f);
            h1[q + 4] = (_Float16)fmaxf(v3[q], 0.f);
        }
        *(hx8*)&H[(size_t)r * 256 + tx * 8]       = h0;
        *(hx8*)&H[(size_t)r * 256 + tx * 8 + 128] = h1;
    }
}

// gemm2 MFMA: Z[N,256] = fp16( H[N,256] @ W2 ), 128x128 tile, BK=64, dbuf LDS.
#define LDH 72
__global__ __launch_bounds__(256, 2) void k_gemm2m(const _Float16* __restrict__ A,
                                                   const _Float16* __restrict__ Bt,
                                                   _Float16* __restrict__ Z) {
    __shared__ __align__(16) _Float16 As[2][128 * LDH];
    __shared__ __align__(16) _Float16 Bs[2][128 * LDH];
    int tid = threadIdx.x;
    int lane = tid & 63, wid = tid >> 6;
    int wm = wid >> 1, wn = wid & 1;
    int row0 = blockIdx.x * 128, col0 = blockIdx.y * 128;
    int l15 = lane & 15, g = lane >> 4;
    int sr = tid >> 3, sc = tid & 7;

    fx4 acc[4][4];
    #pragma unroll
    for (int m = 0; m < 4; m++)
        #pragma unroll
        for (int n = 0; n < 4; n++) acc[m][n] = (fx4){0.f, 0.f, 0.f, 0.f};

    uint4 ga[4], gb[4];
    #pragma unroll
    for (int it = 0; it < 4; it++) {
        ga[it] = *(const uint4*)&A[(size_t)(row0 + sr + 32 * it) * 256 + sc * 8];
        gb[it] = *(const uint4*)&Bt[(size_t)(col0 + sr + 32 * it) * 256 + sc * 8];
    }
    #pragma unroll
    for (int it = 0; it < 4; it++) {
        *(uint4*)&As[0][(sr + 32 * it) * LDH + sc * 8] = ga[it];
        *(uint4*)&Bs[0][(sr + 32 * it) * LDH + sc * 8] = gb[it];
    }
    __syncthreads();

    int cur = 0;
    for (int t = 0; t < 4; t++) {
        if (t < 3) {
            int k0 = (t + 1) * 64;
            #pragma unroll
            for (int it = 0; it < 4; it++) {
                ga[it] = *(const uint4*)&A[(size_t)(row0 + sr + 32 * it) * 256 + k0 + sc * 8];
                gb[it] = *(const uint4*)&Bt[(size_t)(col0 + sr + 32 * it) * 256 + k0 + sc * 8];
            }
        }
        const _Float16* ap = As[cur];
        const _Float16* bp = Bs[cur];
        hx8 af[4][2], bf[4][2];
        #pragma unroll
        for (int m = 0; m < 4; m++)
            #pragma unroll
            for (int ks = 0; ks < 2; ks++)
                af[m][ks] = *(const hx8*)&ap[(wm * 64 + m * 16 + l15) * LDH + ks * 32 + g * 8];
        #pragma unroll
        for (int n = 0; n < 4; n++)
            #pragma unroll
            for (int ks = 0; ks < 2; ks++)
                bf[n][ks] = *(const hx8*)&bp[(wn * 64 + n * 16 + l15) * LDH + ks * 32 + g * 8];
        #pragma unroll
        for (int m = 0; m < 4; m++)
            #pragma unroll
            for (int n = 0; n < 4; n++) {
                acc[m][n] = __builtin_amdgcn_mfma_f32_16x16x32_f16(af[m][0], bf[n][0], acc[m][n], 0, 0, 0);
                acc[m][n] = __builtin_amdgcn_mfma_f32_16x16x32_f16(af[m][1], bf[n][1], acc[m][n], 0, 0, 0);
            }
        if (t < 3) {
            #pragma unroll
            for (int it = 0; it < 4; it++) {
                *(uint4*)&As[cur ^ 1][(sr + 32 * it) * LDH + sc * 8] = ga[it];
                *(uint4*)&Bs[cur ^ 1][(sr + 32 * it) * LDH + sc * 8] = gb[it];
            }
        }
        __syncthreads();
        cur ^= 1;
    }

    #pragma unroll
    for (int m = 0; m < 4; m++)
        #pragma unroll
        for (int n = 0; n < 4; n++) {
            int cc = col0 + wn * 64 + n * 16 + l15;
            #pragma unroll
            for (int r = 0; r < 4; r++) {
                int rr = row0 + wm * 64 + m * 16 + g * 4 + r;
                Z[(size_t)rr * 256 + cc] = (_Float16)acc[m][n][r];
            }
        }
}

// agg2 + mean fused (R9 version — known best): wave handles 8 consecutive
// nodes sequentially, running sum of relu(acc + b2) in registers; block
// (4 waves x 8 nodes = 32 nodes, one batch) LDS-reduces, ONE atomic per lane.
// Full wave per row (64 lanes x hx4 = 512 B), 8 rows in flight per iter.
__global__ __launch_bounds__(256) void k_aggm(const _Float16* __restrict__ Z, const int* __restrict__ indptr,
                                              const int* __restrict__ csrc, const float* __restrict__ dinv,
                                              const float* __restrict__ bias, float* __restrict__ pooled) {
    __shared__ float ps[4][256];
    int tid = threadIdx.x;
    int wid = tid >> 6, lane = tid & 63;
    int n0 = blockIdx.x * 32 + wid * 8;
    fx4 bb = *(const fx4*)&bias[lane * 4];
    fx4 racc = (fx4){0.f, 0.f, 0.f, 0.f};
    #pragma unroll 1
    for (int u = 0; u < 8; u++) {
        int n = n0 + u;
        int beg = indptr[n];
        int cnt8 = indptr[n + 1] - beg;     // multiple of 8 (padded lists)
        float dn = dinv[n];
        const int* cs = csrc + beg;
        fx4 acc = (fx4){0.f, 0.f, 0.f, 0.f};
        for (int i = 0; i < cnt8; i += 8) {
            int4 ia = *(const int4*)&cs[i];
            int4 ib = *(const int4*)&cs[i + 4];
            float m0 = dinv[ia.x] * dn, m1 = dinv[ia.y] * dn;
            float m2 = dinv[ia.z] * dn, m3 = dinv[ia.w] * dn;
            float m4 = dinv[ib.x] * dn, m5 = dinv[ib.y] * dn;
            float m6 = dinv[ib.z] * dn, m7 = dinv[ib.w] * dn;
            hx4 v0 = *(const hx4*)&Z[(size_t)ia.x * 256 + lane * 4];
            hx4 v1 = *(const hx4*)&Z[(size_t)ia.y * 256 + lane * 4];
            hx4 v2 = *(const hx4*)&Z[(size_t)ia.z * 256 + lane * 4];
            hx4 v3 = *(const hx4*)&Z[(size_t)ia.w * 256 + lane * 4];
            hx4 v4 = *(const hx4*)&Z[(size_t)ib.x * 256 + lane * 4];
            hx4 v5 = *(const hx4*)&Z[(size_t)ib.y * 256 + lane * 4];
            hx4 v6 = *(const hx4*)&Z[(size_t)ib.z * 256 + lane * 4];
            hx4 v7 = *(const hx4*)&Z[(size_t)ib.w * 256 + lane * 4];
            ACC4(v0, m0)
            ACC4(v1, m1)
            ACC4(v2, m2)
            ACC4(v3, m3)
            ACC4(v4, m4)
            ACC4(v5, m5)
            ACC4(v6, m6)
            ACC4(v7, m7)
        }
        acc += bb;
        racc.x += fmaxf(acc.x, 0.f); racc.y += fmaxf(acc.y, 0.f);
        racc.z += fmaxf(acc.z, 0.f); racc.w += fmaxf(acc.w, 0.f);
    }
    *(fx4*)&ps[wid][lane * 4] = racc;
    __syncthreads();
    float s = ps[0][tid] + ps[1][tid] + ps[2][tid] + ps[3][tid];
    atomicAdd(&pooled[(blockIdx.x >> 4) * 256 + tid], s * (1.f / 512.f));
}

__global__ __launch_bounds__(64) void k_cls(const float* __restrict__ pooled, const float* __restrict__ cw,
                                            const float* __restrict__ cb, float* __restrict__ outp) {
    int b = blockIdx.x, lane = threadIdx.x;
    float po[10];
    #pragma unroll
    for (int o = 0; o < 10; o++) po[o] = 0.f;
    #pragma unroll
    for (int m = 0; m < 4; m++) {
        int hh = lane + m * 64;
        float ph = pooled[b * HID + hh];
        #pragma unroll
        for (int o = 0; o < 10; o++) po[o] = fmaf(ph, cw[hh * 10 + o], po[o]);
    }
    #pragma unroll
    for (int off = 32; off >= 1; off >>= 1) {
        #pragma unroll
        for (int o = 0; o < 10; o++) po[o] += __shfl_down(po[o], off);
    }
    if (lane == 0) {
        #pragma unroll
        for (int o = 0; o < 10; o++) outp[b * 10 + o] = po[o] + cb[o];
    }
}

extern "C" void kernel_launch(void* const* d_in, const int* in_sizes, int n_in,
                              void* d_out, int out_size, void* d_ws, size_t ws_size,
                              hipStream_t stream) {
    const float* x   = (const float*)d_in[0];
    const int*   ei  = (const int*)d_in[1];
    const float* w1  = (const float*)d_in[2];
    const float* b1  = (const float*)d_in[3];
    const float* w2  = (const float*)d_in[4];
    const float* b2  = (const float*)d_in[5];
    const float* g1w = (const float*)d_in[6];
    const float* g1b = (const float*)d_in[7];
    const float* g2w = (const float*)d_in[8];
    const float* g2b = (const float*)d_in[9];
    const float* cw  = (const float*)d_in[10];
    const float* cb  = (const float*)d_in[11];
    float* out = (float*)d_out;
    char* ws = (char*)d_ws;

    _Float16*       H      = (_Float16*)(ws + OFF_H);
    _Float16*       Z      = (_Float16*)(ws + OFF_Z);
    float*          h1     = (float*)(ws + OFF_H1);
    _Float16*       xn     = (_Float16*)(ws + OFF_XN);
    float*          y1     = (float*)(ws + OFF_Y1);
    int*            deg    = (int*)(ws + OFF_DEG);
    int*            indptr = (int*)(ws + OFF_INDPTR);
    int*            cnt    = (int*)(ws + OFF_CNT);
    float*          dinv   = (float*)(ws + OFF_DINV);
    int*            csrc   = (int*)(ws + OFF_CSRC);
    float*          wt1    = (float*)(ws + OFF_WT1);
    float*          wt2    = (float*)(ws + OFF_WT2);
    float*          pooled = (float*)(ws + OFF_POOL);
    _Float16*       w2t    = (_Float16*)(ws + OFF_W2T);
    unsigned*       xnz    = (unsigned*)(xn + (size_t)NN * 32);      // dummy row NN of xn
    unsigned*       zz     = (unsigned*)(Z + (size_t)NN * 256);      // dummy row NN of Z

    k_setup <<<174, 256, 0, stream>>>(deg, cnt, pooled, w1, w2, wt1, wt2, g2w, w2t, xnz, zz);
    k_c1cnt <<<1024, 256, 0, stream>>>(x, wt1, b1, h1, ei, deg);             // conv1 || count
    k_scan  <<<1, 1024, 0, stream>>>(deg, indptr, dinv);
    k_c2fill<<<1280, 256, 0, stream>>>(h1, wt2, b2, xn, ei, deg, indptr, cnt, csrc);  // conv2 || fill
    k_agg32 <<<8192, 256, 0, stream>>>(xn, indptr, csrc, dinv, y1);          // y1 = A^ . X (32-wide)
    k_gemm1 <<<512, 256, 0, stream>>>(y1, g1w, g1b, H);                      // H = fp16(relu(y1@W1+b1))
    k_gemm2m<<<dim3(256, 2), 256, 0, stream>>>(H, w2t, Z);                   // Z = fp16(H@W2)
    k_aggm  <<<1024, 256, 0, stream>>>(Z, indptr, csrc, dinv, g2b, pooled);  // pooled += relu(A^ . Z + b2)/512
    k_cls   <<<64, 64, 0, stream>>>(pooled, cw, cb, out);
}

// Round 12
// 176.065 us; speedup vs baseline: 1.3701x; 1.0915x over previous
//
#include <hip/hip_runtime.h>

#define B_ 64
#define CIN 64
#define T_ 2048
#define C1 16
#define T1 1024
#define C2 32
#define T2 512
#define NN 32768
#define HID 256
#define OUTD 10
#define NE 524288
#define NTOT (NE + NN)          // 557056

typedef __attribute__((ext_vector_type(4))) float fx4;
typedef __attribute__((ext_vector_type(8))) _Float16 hx8;
typedef __attribute__((ext_vector_type(4))) _Float16 hx4;
typedef __attribute__((ext_vector_type(2))) _Float16 hx2;

// ---- workspace byte offsets (ends ~51.5 MB; ws proven >= 75 MB) ----
#define OFF_H      (0ull)                    // 16 MB: H fp16 [N][256]
#define OFF_Z      (16ull<<20)               // 16 MB + 64K: Z fp16 [N+1][256] (row NN = zero dummy)
#define OFF_H1     (33ull<<20)               // 4 MB: conv1 out
#define OFF_XN     (37ull<<20)               // 2 MB + 64B: xn fp16 [N+1][32] (row NN = zero dummy)
#define OFF_Y1     (42ull<<20)               // 4 MB: agg1 out fp32 [N][32]
#define OFF_DEG    (46ull<<20)               // 128 KB int
#define OFF_INDPTR ((46ull<<20) + (256u<<10))
#define OFF_CNT    ((46ull<<20) + (512u<<10))
#define OFF_DINV   ((46ull<<20) + (768u<<10))   // [N+1] floats
#define OFF_CSRC   (47ull<<20)               // padded CSR src, cap 3.25 MB
#define OFF_WT1    (51ull<<20)               // 20 KB
#define OFF_WT2    (OFF_WT1 + (64u<<10))
#define OFF_POOL   (OFF_WT1 + (128u<<10))
#define OFF_W2T    (OFF_WT1 + (256u<<10))    // 128 KB: W2^T fp16

__device__ __forceinline__ fx4 shfl_xor4(fx4 v, int m) {
    return (fx4){__shfl_xor(v.x, m), __shfl_xor(v.y, m), __shfl_xor(v.z, m), __shfl_xor(v.w, m)};
}

// setup: blocks 0..127 init deg/cnt/pooled (+zero dummy rows of xn, Z);
// 128..143 cvtw (W2->W2T fp16); 144..173 twt (conv weight transpose)
__global__ __launch_bounds__(256) void k_setup(int* deg, int* cnt, float* pooled,
                                               const float* __restrict__ w1, const float* __restrict__ w2,
                                               float* __restrict__ wt1, float* __restrict__ wt2,
                                               const float* __restrict__ gw2, _Float16* __restrict__ w2t,
                                               unsigned* __restrict__ xnz, unsigned* __restrict__ zz) {
    __shared__ float tl[64][65];
    int blk = blockIdx.x, t = threadIdx.x;
    if (blk < 128) {
        int i = blk * 256 + t;
        if (i < NN) { deg[i] = 1; cnt[i] = 0; }   // deg starts at 1 (self-loop)
        if (i < B_ * HID) pooled[i] = 0.f;
        if (blk == 0 && t < 16) xnz[t] = 0u;      // xn dummy row NN (64 B fp16)
        if (blk == 1 && t < 128) zz[t] = 0u;      // Z dummy row NN (512 B)
    } else if (blk < 144) {
        int bb = blk - 128;
        int bx = bb & 3, by = bb >> 2;            // k-tile, n-tile
        #pragma unroll
        for (int it = 0; it < 16; it++) {
            int idx = it * 256 + t;
            int r = idx >> 6, c = idx & 63;
            tl[r][c] = gw2[(size_t)(bx * 64 + r) * 256 + by * 64 + c];
        }
        __syncthreads();
        #pragma unroll
        for (int it = 0; it < 16; it++) {
            int idx = it * 256 + t;
            int r = idx >> 6, c = idx & 63;
            w2t[(size_t)(by * 64 + r) * 256 + bx * 64 + c] = (_Float16)tl[c][r];
        }
    } else {
        int i = (blk - 144) * 256 + t;
        if (i < 16 * 64 * 5) {
            int co = i & 15; int r = i >> 4; int k = r % 5; int ci = r / 5;
            wt1[i] = w1[(co * 64 + ci) * 5 + k];
        }
        int j = i - 16 * 64 * 5;
        if (j >= 0 && j < 32 * 16 * 5) {
            int co = j & 31; int r = j >> 5; int k = r % 5; int ci = r / 5;
            wt2[j] = w2[(co * 16 + ci) * 5 + k];
        }
    }
}

// scan over PADDED degrees ((deg+7)&~7); emits dinv = rsqrt(real deg), dinv[NN]=0.
__global__ __launch_bounds__(1024) void k_scan(const int* __restrict__ deg, int* __restrict__ indptr,
                                               float* __restrict__ dinv) {
    __shared__ int wsum[16];
    int tid = threadIdx.x;
    int lane = tid & 63, w = tid >> 6;
    int base = tid * 32;
    int loc[32]; int s = 0;
    #pragma unroll
    for (int j = 0; j < 32; j++) {
        int d = deg[base + j];
        dinv[base + j] = rsqrtf((float)d);
        loc[j] = d;
        s += (d + 7) & ~7;
    }
    int v = s;                       // inclusive wave scan
    #pragma unroll
    for (int off = 1; off < 64; off <<= 1) {
        int t = __shfl_up(v, off);
        if (lane >= off) v += t;
    }
    if (lane == 63) wsum[w] = v;
    __syncthreads();
    int woff = 0;
    #pragma unroll
    for (int i = 0; i < 16; i++) { int t = wsum[i]; if (i < w) woff += t; }
    int run = woff + v - s;          // exclusive prefix for this thread
    #pragma unroll
    for (int j = 0; j < 32; j++) { indptr[base + j] = run; run += (loc[j] + 7) & ~7; }
    if (tid == 1023) { indptr[NN] = run; dinv[NN] = 0.f; }
}

// FUSED conv1(MFMA implicit GEMM) + count.
// Blocks 0..511: conv1 tile (tile=blk&7, b=blk>>3): M=256 t-rows, N=16 co,
//   K=320 (kk*64+ci order). x staged transposed fp16 xs[j=t+2][ci] with
//   (j>>3)&7 XOR swizzle on ci-blocks (kills transpose-write AND frag-read
//   bank conflicts); weights wl[co][K] fp16 (K-contiguous fragments).
// Blocks 512..1023: degree-count, 4 edges/thread (int4).
#define LDX 72
__global__ __launch_bounds__(256) void k_c1cnt(const float* __restrict__ x, const float* __restrict__ wt1,
                                               const float* __restrict__ b1, float* __restrict__ h1,
                                               const int* __restrict__ ei, int* __restrict__ deg) {
    int blk = blockIdx.x;
    int tid = threadIdx.x;
    if (blk >= 512) {
        int t = (blk - 512) * 256 + tid;   // < NE/4
        int4 d4 = *(const int4*)&ei[NE + 4 * t];
        atomicAdd(&deg[d4.x], 1);
        atomicAdd(&deg[d4.y], 1);
        atomicAdd(&deg[d4.z], 1);
        atomicAdd(&deg[d4.w], 1);
        return;
    }
    __shared__ _Float16 xs[260 * LDX];   // xs[j][ci-swizzled], j = t+2
    __shared__ _Float16 wl[16 * 328];    // wl[co][K], K = kk*64+ci
    __shared__ float ps2[128 * 17];      // pooled out bounce [t1][co]
    int tile = blk & 7;
    int b = blk >> 3;
    int t0 = tile * 256;
    const float* xb = x + ((size_t)b * CIN) * T_ + t0;
    {   // interior cols: lane f covers t 4f..4f+3 of row ci=r -> transposed write
        int f = tid & 63, r0 = tid >> 6;
        #pragma unroll
        for (int it = 0; it < 16; it++) {
            int r = r0 + 4 * it;                       // ci
            fx4 v = *(const fx4*)&xb[(size_t)r * T_ + f * 4];
            #pragma unroll
            for (int q = 0; q < 4; q++) {
                int j = 2 + f * 4 + q;
                xs[j * LDX + ((((r >> 3) ^ (j >> 3)) & 7) << 3) + (r & 7)] = (_Float16)v[q];
            }
        }
        // halo j in {0,1,258,259} (sw(j)=0 there): 1 value per thread
        int r = tid >> 2, c = tid & 3;
        int off = (c < 2) ? (c - 2) : (254 + c);
        int gt = t0 + off;
        float v = 0.f;
        if (gt >= 0 && gt < T_) v = xb[(size_t)r * T_ + off];
        xs[(off + 2) * LDX + r] = (_Float16)v;
        // weights: wl[co][K=kk*64+ci] <- wt1[(ci*5+kk)*16+co]
        for (int i = tid; i < 5120; i += 256) {
            int K = i >> 4, co = i & 15;
            int kk = K >> 6, ci = K & 63;
            wl[co * 328 + K] = (_Float16)wt1[(ci * 5 + kk) * 16 + co];
        }
    }
    __syncthreads();
    int wv = tid >> 6, lane = tid & 63;
    int l15 = lane & 15, g = lane >> 4;
    fx4 acc[4];
    #pragma unroll
    for (int m = 0; m < 4; m++) acc[m] = (fx4){0.f, 0.f, 0.f, 0.f};
    #pragma unroll
    for (int ks = 0; ks < 10; ks++) {
        int kk = ks >> 1;
        int cb = (ks & 1) * 4 + g;                  // ci 8-block index 0..7
        hx8 bf = *(const hx8*)&wl[l15 * 328 + ks * 32 + g * 8];
        #pragma unroll
        for (int m = 0; m < 4; m++) {
            int j = wv * 64 + m * 16 + l15 + kk;    // A row (t + kk), +2-2 folded
            hx8 af = *(const hx8*)&xs[j * LDX + ((((j >> 3) & 7) ^ cb) << 3)];
            acc[m] = __builtin_amdgcn_mfma_f32_16x16x32_f16(af, bf, acc[m], 0, 0, 0);
        }
    }
    // bias + relu + pool2 in-register: C rows g*4+r pair up within the lane
    float bv = b1[l15];
    #pragma unroll
    for (int m = 0; m < 4; m++) {
        int t1b = wv * 32 + m * 8 + g * 2;
        float a0 = fmaxf(acc[m][0] + bv, 0.f);
        float a1 = fmaxf(acc[m][1] + bv, 0.f);
        float a2 = fmaxf(acc[m][2] + bv, 0.f);
        float a3 = fmaxf(acc[m][3] + bv, 0.f);
        ps2[t1b * 17 + l15] = fmaxf(a0, a1);
        ps2[(t1b + 1) * 17 + l15] = fmaxf(a2, a3);
    }
    __syncthreads();
    for (int idx = tid; idx < 2048; idx += 256) {
        int t1 = idx & 127, co = idx >> 7;
        h1[(b * C1 + co) * T1 + tile * 128 + t1] = ps2[t1 * 17 + co];
    }
}

// FUSED conv2 + fill. Blocks 0..255: conv2 (tile=blk&3, b=blk>>2) -> xn fp16.
// Blocks 256..1023: CSR fill (4 edges/thread int4; self-loops; pad sentinels).
__global__ __launch_bounds__(256) void k_c2fill(const float* __restrict__ h1, const float* __restrict__ wt2,
                                                const float* __restrict__ b2, _Float16* __restrict__ xn,
                                                const int* __restrict__ ei, const int* __restrict__ deg,
                                                const int* __restrict__ indptr, int* __restrict__ cnt,
                                                int* __restrict__ csrc) {
    int blk = blockIdx.x;
    int tid = threadIdx.x;
    if (blk >= 256) {
        int t = (blk - 256) * 256 + tid;
        if (t < NE / 4) {
            int4 s4 = *(const int4*)&ei[4 * t];
            int4 d4 = *(const int4*)&ei[NE + 4 * t];
            int p0 = indptr[d4.x] + atomicAdd(&cnt[d4.x], 1); csrc[p0] = s4.x;
            int p1 = indptr[d4.y] + atomicAdd(&cnt[d4.y], 1); csrc[p1] = s4.y;
            int p2 = indptr[d4.z] + atomicAdd(&cnt[d4.z], 1); csrc[p2] = s4.z;
            int p3 = indptr[d4.w] + atomicAdd(&cnt[d4.w], 1); csrc[p3] = s4.w;
        } else if (t < NE / 4 + NN) {
            int n = t - NE / 4;
            int pos = indptr[n] + atomicAdd(&cnt[n], 1);
            csrc[pos] = n;
        } else {
            int n = t - NE / 4 - NN;
            if (n < NN) {
                int dd = deg[n], dp = (dd + 7) & ~7, base = indptr[n];
                for (int j = dd; j < dp; j++) csrc[base + j] = NN;
            }
        }
        return;
    }
    __shared__ float xs[16][260];
    __shared__ float ps[128 * 32];
    int tile = blk & 3;
    int b = blk >> 2;
    int t0 = tile * 256;
    float acc[32];
    #pragma unroll
    for (int i = 0; i < 32; i++) acc[i] = 0.f;
    for (int idx = tid; idx < 16 * 260; idx += 256) {
        int r = idx / 260, c = idx % 260;
        int gt = t0 + c - 2;
        float v = 0.f;
        if (gt >= 0 && gt < T1) v = h1[(b * C1 + r) * T1 + gt];
        xs[r][c] = v;
    }
    __syncthreads();
    for (int ci = 0; ci < 16; ci++) {
        float xv[5];
        #pragma unroll
        for (int j = 0; j < 5; j++) xv[j] = xs[ci][tid + j];
        const float* wp = wt2 + (ci * 5) * 32;
        #pragma unroll
        for (int k = 0; k < 5; k++) {
            #pragma unroll
            for (int co = 0; co < 32; co++)
                acc[co] = fmaf(xv[k], wp[k * 32 + co], acc[co]);
        }
    }
    #pragma unroll
    for (int co = 0; co < 32; co++) {
        float a = fmaxf(acc[co] + b2[co], 0.f);
        float o = fmaxf(a, __shfl_xor(a, 1));
        if ((tid & 1) == 0) ps[(tid >> 1) * 32 + co] = o;
    }
    __syncthreads();
    size_t base = ((size_t)b * T2 + tile * 128) * 32;
    for (int idx = tid; idx < 128 * 16; idx += 256) {
        hx2 h;
        h.x = (_Float16)ps[2 * idx];
        h.y = (_Float16)ps[2 * idx + 1];
        *(hx2*)&xn[base + 2 * idx] = h;
    }
}

#define ACC4(v, m) \
    acc.x = fmaf((float)v[0], m, acc.x); acc.y = fmaf((float)v[1], m, acc.y); \
    acc.z = fmaf((float)v[2], m, acc.z); acc.w = fmaf((float)v[3], m, acc.w);

// agg1: y1[n,:] = sum_e dinv[s]*dinv[n] * xn[s,:]; xn fp16 (2 MB, L2-resident).
// Wave per node: 8 edge-slots x 8 lanes x hx4, shfl reduce.
__global__ __launch_bounds__(256) void k_agg32(const _Float16* __restrict__ xn, const int* __restrict__ indptr,
                                               const int* __restrict__ csrc, const float* __restrict__ dinv,
                                               float* __restrict__ y1) {
    int lane = threadIdx.x & 63;
    int n = blockIdx.x * 4 + (threadIdx.x >> 6);
    int eg = lane >> 3, fi = lane & 7;
    int beg = indptr[n];
    int cnt8 = indptr[n + 1] - beg;     // multiple of 8
    float dn = dinv[n];
    const int* cs = csrc + beg;
    fx4 acc = (fx4){0.f, 0.f, 0.f, 0.f};
    for (int i = 0; i < cnt8; i += 8) {
        int s = cs[i + eg];
        float m = dinv[s] * dn;
        hx4 v = *(const hx4*)&xn[(size_t)s * 32 + fi * 4];
        ACC4(v, m)
    }
    acc += shfl_xor4(acc, 8);
    acc += shfl_xor4(acc, 16);
    acc += shfl_xor4(acc, 32);
    if (lane < 8) *(fx4*)&y1[(size_t)n * 32 + fi * 4] = acc;
}

// gemm1: H[N,256] = fp16( relu(y1[N,32] @ W1[32,256] + b1) ); 64-row tiles.
__global__ __launch_bounds__(256) void k_gemm1(const float* __restrict__ A, const float* __restrict__ W,
                                               const float* __restrict__ bias, _Float16* __restrict__ H) {
    __shared__ __align__(16) float xT[32 * 68];   // [k][r], 64 rows + pad
    __shared__ __align__(16) float wl[32 * 256];
    int tid = threadIdx.x;
    int ty = tid >> 4, tx = tid & 15;
    int rows0 = blockIdx.x * 64;
    int kq = tid & 7, rs = tid >> 3;              // staging coords (rs 0..31)
    {
        fx4 v0 = *(const fx4*)&A[(size_t)(rows0 + rs) * 32 + kq * 4];
        fx4 v1 = *(const fx4*)&A[(size_t)(rows0 + rs + 32) * 32 + kq * 4];
        #pragma unroll
        for (int i = 0; i < 4; i++) {
            xT[(kq * 4 + i) * 68 + rs]      = v0[i];
            xT[(kq * 4 + i) * 68 + rs + 32] = v1[i];
        }
    }
    #pragma unroll
    for (int m = 0; m < 8; m++)
        *(fx4*)&wl[m * 1024 + tid * 4] = *(const fx4*)&W[(size_t)(m * 1024 + tid * 4)];
    __syncthreads();

    fx4 c[4][4];
    #pragma unroll
    for (int i = 0; i < 4; i++)
        #pragma unroll
        for (int j = 0; j < 4; j++) c[i][j] = (fx4){0.f, 0.f, 0.f, 0.f};

    #pragma unroll 8
    for (int kk = 0; kk < 32; kk++) {
        fx4 xa = *(const fx4*)&xT[kk * 68 + ty * 4];
        fx4 w[4];
        w[0] = *(const fx4*)&wl[kk * 256 + tx * 8];
        w[1] = *(const fx4*)&wl[kk * 256 + tx * 8 + 4];
        w[2] = *(const fx4*)&wl[kk * 256 + tx * 8 + 128];
        w[3] = *(const fx4*)&wl[kk * 256 + tx * 8 + 132];
        #pragma unroll
        for (int j = 0; j < 4; j++) {
            c[0][j] += xa.x * w[j];
            c[1][j] += xa.y * w[j];
            c[2][j] += xa.z * w[j];
            c[3][j] += xa.w * w[j];
        }
    }
    fx4 bb[4];
    bb[0] = *(const fx4*)&bias[tx * 8];
    bb[1] = *(const fx4*)&bias[tx * 8 + 4];
    bb[2] = *(const fx4*)&bias[tx * 8 + 128];
    bb[3] = *(const fx4*)&bias[tx * 8 + 132];
    #pragma unroll
    for (int i = 0; i < 4; i++) {
        int r = rows0 + ty * 4 + i;
        fx4 v0 = c[i][0] + bb[0], v1 = c[i][1] + bb[1];
        fx4 v2 = c[i][2] + bb[2], v3 = c[i][3] + bb[3];
        hx8 h0, h1;
        #pragma unroll
        for (int q = 0; q < 4; q++) {
            h0[q]     = (_Float16)fmaxf(v0[q], 0.f);
            h0[q + 4] = (_Float16)fmaxf(v1[q], 0.f);
            h1[q]     = (_Float16)fmaxf(v2[q], 0.f);
            h1[q + 4] = (_Float16)fmaxf(v3[q], 0.f);
        }
        *(hx8*)&H[(size_t)r * 256 + tx * 8]       = h0;
        *(hx8*)&H[(size_t)r * 256 + tx * 8 + 128] = h1;
    }
}

// gemm2 MFMA: Z[N,256] = fp16( H[N,256] @ W2 ), 128x128 tile, BK=64, dbuf LDS.
#define LDH 72
__global__ __launch_bounds__(256, 2) void k_gemm2m(const _Float16* __restrict__ A,
                                                   const _Float16* __restrict__ Bt,
                                                   _Float16* __restrict__ Z) {
    __shared__ __align__(16) _Float16 As[2][128 * LDH];
    __shared__ __align__(16) _Float16 Bs[2][128 * LDH];
    int tid = threadIdx.x;
    int lane = tid & 63, wid = tid >> 6;
    int wm = wid >> 1, wn = wid & 1;
    int row0 = blockIdx.x * 128, col0 = blockIdx.y * 128;
    int l15 = lane & 15, g = lane >> 4;
    int sr = tid >> 3, sc = tid & 7;

    fx4 acc[4][4];
    #pragma unroll
    for (int m = 0; m < 4; m++)
        #pragma unroll
        for (int n = 0; n < 4; n++) acc[m][n] = (fx4){0.f, 0.f, 0.f, 0.f};

    uint4 ga[4], gb[4];
    #pragma unroll
    for (int it = 0; it < 4; it++) {
        ga[it] = *(const uint4*)&A[(size_t)(row0 + sr + 32 * it) * 256 + sc * 8];
        gb[it] = *(const uint4*)&Bt[(size_t)(col0 + sr + 32 * it) * 256 + sc * 8];
    }
    #pragma unroll
    for (int it = 0; it < 4; it++) {
        *(uint4*)&As[0][(sr + 32 * it) * LDH + sc * 8] = ga[it];
        *(uint4*)&Bs[0][(sr + 32 * it) * LDH + sc * 8] = gb[it];
    }
    __syncthreads();

    int cur = 0;
    for (int t = 0; t < 4; t++) {
        if (t < 3) {
            int k0 = (t + 1) * 64;
            #pragma unroll
            for (int it = 0; it < 4; it++) {
                ga[it] = *(const uint4*)&A[(size_t)(row0 + sr + 32 * it) * 256 + k0 + sc * 8];
                gb[it] = *(const uint4*)&Bt[(size_t)(col0 + sr + 32 * it) * 256 + k0 + sc * 8];
            }
        }
        const _Float16* ap = As[cur];
        const _Float16* bp = Bs[cur];
        hx8 af[4][2], bf[4][2];
        #pragma unroll
        for (int m = 0; m < 4; m++)
            #pragma unroll
            for (int ks = 0; ks < 2; ks++)
                af[m][ks] = *(const hx8*)&ap[(wm * 64 + m * 16 + l15) * LDH + ks * 32 + g * 8];
        #pragma unroll
        for (int n = 0; n < 4; n++)
            #pragma unroll
            for (int ks = 0; ks < 2; ks++)
                bf[n][ks] = *(const hx8*)&bp[(wn * 64 + n * 16 + l15) * LDH + ks * 32 + g * 8];
        #pragma unroll
        for (int m = 0; m < 4; m++)
            #pragma unroll
            for (int n = 0; n < 4; n++) {
                acc[m][n] = __builtin_amdgcn_mfma_f32_16x16x32_f16(af[m][0], bf[n][0], acc[m][n], 0, 0, 0);
                acc[m][n] = __builtin_amdgcn_mfma_f32_16x16x32_f16(af[m][1], bf[n][1], acc[m][n], 0, 0, 0);
            }
        if (t < 3) {
            #pragma unroll
            for (int it = 0; it < 4; it++) {
                *(uint4*)&As[cur ^ 1][(sr + 32 * it) * LDH + sc * 8] = ga[it];
                *(uint4*)&Bs[cur ^ 1][(sr + 32 * it) * LDH + sc * 8] = gb[it];
            }
        }
        __syncthreads();
        cur ^= 1;
    }

    #pragma unroll
    for (int m = 0; m < 4; m++)
        #pragma unroll
        for (int n = 0; n < 4; n++) {
            int cc = col0 + wn * 64 + n * 16 + l15;
            #pragma unroll
            for (int r = 0; r < 4; r++) {
                int rr = row0 + wm * 64 + m * 16 + g * 4 + r;
                Z[(size_t)rr * 256 + cc] = (_Float16)acc[m][n][r];
            }
        }
}

// agg2 + mean fused: wave handles 8 consecutive nodes sequentially, running
// sum of relu(acc + b2) in registers; block (4 waves x 8 nodes = 32 nodes,
// one batch) LDS-reduces, ONE atomic per lane. Full wave per row (64 lanes x
// hx4 = 512 B), 8 rows in flight per iter.
__global__ __launch_bounds__(256) void k_aggm(const _Float16* __restrict__ Z, const int* __restrict__ indptr,
                                              const int* __restrict__ csrc, const float* __restrict__ dinv,
                                              const float* __restrict__ bias, float* __restrict__ pooled) {
    __shared__ float ps[4][256];
    int tid = threadIdx.x;
    int wid = tid >> 6, lane = tid & 63;
    int n0 = blockIdx.x * 32 + wid * 8;
    fx4 bb = *(const fx4*)&bias[lane * 4];
    fx4 racc = (fx4){0.f, 0.f, 0.f, 0.f};
    #pragma unroll 1
    for (int u = 0; u < 8; u++) {
        int n = n0 + u;
        int beg = indptr[n];
        int cnt8 = indptr[n + 1] - beg;     // multiple of 8 (padded lists)
        float dn = dinv[n];
        const int* cs = csrc + beg;
        fx4 acc = (fx4){0.f, 0.f, 0.f, 0.f};
        for (int i = 0; i < cnt8; i += 8) {
            int4 ia = *(const int4*)&cs[i];
            int4 ib = *(const int4*)&cs[i + 4];
            float m0 = dinv[ia.x] * dn, m1 = dinv[ia.y] * dn;
            float m2 = dinv[ia.z] * dn, m3 = dinv[ia.w] * dn;
            float m4 = dinv[ib.x] * dn, m5 = dinv[ib.y] * dn;
            float m6 = dinv[ib.z] * dn, m7 = dinv[ib.w] * dn;
            hx4 v0 = *(const hx4*)&Z[(size_t)ia.x * 256 + lane * 4];
            hx4 v1 = *(const hx4*)&Z[(size_t)ia.y * 256 + lane * 4];
            hx4 v2 = *(const hx4*)&Z[(size_t)ia.z * 256 + lane * 4];
            hx4 v3 = *(const hx4*)&Z[(size_t)ia.w * 256 + lane * 4];
            hx4 v4 = *(const hx4*)&Z[(size_t)ib.x * 256 + lane * 4];
            hx4 v5 = *(const hx4*)&Z[(size_t)ib.y * 256 + lane * 4];
            hx4 v6 = *(const hx4*)&Z[(size_t)ib.z * 256 + lane * 4];
            hx4 v7 = *(const hx4*)&Z[(size_t)ib.w * 256 + lane * 4];
            ACC4(v0, m0)
            ACC4(v1, m1)
            ACC4(v2, m2)
            ACC4(v3, m3)
            ACC4(v4, m4)
            ACC4(v5, m5)
            ACC4(v6, m6)
            ACC4(v7, m7)
        }
        acc += bb;
        racc.x += fmaxf(acc.x, 0.f); racc.y += fmaxf(acc.y, 0.f);
        racc.z += fmaxf(acc.z, 0.f); racc.w += fmaxf(acc.w, 0.f);
    }
    *(fx4*)&ps[wid][lane * 4] = racc;
    __syncthreads();
    float s = ps[0][tid] + ps[1][tid] + ps[2][tid] + ps[3][tid];
    atomicAdd(&pooled[(blockIdx.x >> 4) * 256 + tid], s * (1.f / 512.f));
}

__global__ __launch_bounds__(64) void k_cls(const float* __restrict__ pooled, const float* __restrict__ cw,
                                            const float* __restrict__ cb, float* __restrict__ outp) {
    int b = blockIdx.x, lane = threadIdx.x;
    float po[10];
    #pragma unroll
    for (int o = 0; o < 10; o++) po[o] = 0.f;
    #pragma unroll
    for (int m = 0; m < 4; m++) {
        int hh = lane + m * 64;
        float ph = pooled[b * HID + hh];
        #pragma unroll
        for (int o = 0; o < 10; o++) po[o] = fmaf(ph, cw[hh * 10 + o], po[o]);
    }
    #pragma unroll
    for (int off = 32; off >= 1; off >>= 1) {
        #pragma unroll
        for (int o = 0; o < 10; o++) po[o] += __shfl_down(po[o], off);
    }
    if (lane == 0) {
        #pragma unroll
        for (int o = 0; o < 10; o++) outp[b * 10 + o] = po[o] + cb[o];
    }
}

extern "C" void kernel_launch(void* const* d_in, const int* in_sizes, int n_in,
                              void* d_out, int out_size, void* d_ws, size_t ws_size,
                              hipStream_t stream) {
    const float* x   = (const float*)d_in[0];
    const int*   ei  = (const int*)d_in[1];
    const float* w1  = (const float*)d_in[2];
    const float* b1  = (const float*)d_in[3];
    const float* w2  = (const float*)d_in[4];
    const float* b2  = (const float*)d_in[5];
    const float* g1w = (const float*)d_in[6];
    const float* g1b = (const float*)d_in[7];
    const float* g2w = (const float*)d_in[8];
    const float* g2b = (const float*)d_in[9];
    const float* cw  = (const float*)d_in[10];
    const float* cb  = (const float*)d_in[11];
    float* out = (float*)d_out;
    char* ws = (char*)d_ws;

    _Float16*       H      = (_Float16*)(ws + OFF_H);
    _Float16*       Z      = (_Float16*)(ws + OFF_Z);
    float*          h1     = (float*)(ws + OFF_H1);
    _Float16*       xn     = (_Float16*)(ws + OFF_XN);
    float*          y1     = (float*)(ws + OFF_Y1);
    int*            deg    = (int*)(ws + OFF_DEG);
    int*            indptr = (int*)(ws + OFF_INDPTR);
    int*            cnt    = (int*)(ws + OFF_CNT);
    float*          dinv   = (float*)(ws + OFF_DINV);
    int*            csrc   = (int*)(ws + OFF_CSRC);
    float*          wt1    = (float*)(ws + OFF_WT1);
    float*          wt2    = (float*)(ws + OFF_WT2);
    float*          pooled = (float*)(ws + OFF_POOL);
    _Float16*       w2t    = (_Float16*)(ws + OFF_W2T);
    unsigned*       xnz    = (unsigned*)(xn + (size_t)NN * 32);      // dummy row NN of xn
    unsigned*       zz     = (unsigned*)(Z + (size_t)NN * 256);      // dummy row NN of Z

    k_setup <<<174, 256, 0, stream>>>(deg, cnt, pooled, w1, w2, wt1, wt2, g2w, w2t, xnz, zz);
    k_c1cnt <<<1024, 256, 0, stream>>>(x, wt1, b1, h1, ei, deg);             // conv1(MFMA) || count
    k_scan  <<<1, 1024, 0, stream>>>(deg, indptr, dinv);
    k_c2fill<<<1280, 256, 0, stream>>>(h1, wt2, b2, xn, ei, deg, indptr, cnt, csrc);  // conv2 || fill
    k_agg32 <<<8192, 256, 0, stream>>>(xn, indptr, csrc, dinv, y1);          // y1 = A^ . X (32-wide)
    k_gemm1 <<<512, 256, 0, stream>>>(y1, g1w, g1b, H);                      // H = fp16(relu(y1@W1+b1))
    k_gemm2m<<<dim3(256, 2), 256, 0, stream>>>(H, w2t, Z);                   // Z = fp16(H@W2)
    k_aggm  <<<1024, 256, 0, stream>>>(Z, indptr, csrc, dinv, g2b, pooled);  // pooled += relu(A^ . Z + b2)/512
    k_cls   <<<64, 64, 0, stream>>>(pooled, cw, cb, out);
}

// Round 13
// 166.133 us; speedup vs baseline: 1.4520x; 1.0598x over previous
//
#include <hip/hip_runtime.h>

#define B_ 64
#define CIN 64
#define T_ 2048
#define C1 16
#define T1 1024
#define C2 32
#define T2 512
#define NN 32768
#define HID 256
#define OUTD 10
#define NE 524288
#define NTOT (NE + NN)          // 557056

typedef __attribute__((ext_vector_type(4))) float fx4;
typedef __attribute__((ext_vector_type(8))) _Float16 hx8;
typedef __attribute__((ext_vector_type(4))) _Float16 hx4;
typedef __attribute__((ext_vector_type(2))) _Float16 hx2;

// ---- workspace byte offsets (ends ~51.5 MB; ws proven >= 75 MB) ----
#define OFF_H      (0ull)                    // 16 MB: H fp16 [N][256]
#define OFF_Z      (16ull<<20)               // 16 MB + 64K: Z fp16 [N+1][256] (row NN = zero dummy)
#define OFF_H1     (33ull<<20)               // 4 MB: conv1 out
#define OFF_XN     (37ull<<20)               // 2 MB + 64B: xn fp16 [N+1][32] (row NN = zero dummy)
#define OFF_Y1     (42ull<<20)               // 4 MB: agg1 out fp32 [N][32]
#define OFF_DEG    (46ull<<20)               // 128 KB int
#define OFF_INDPTR ((46ull<<20) + (256u<<10))
#define OFF_CNT    ((46ull<<20) + (512u<<10))
#define OFF_DINV   ((46ull<<20) + (768u<<10))   // [N+1] floats
#define OFF_CSRC   (47ull<<20)               // padded CSR src, cap 3.25 MB
#define OFF_WT1    (51ull<<20)               // 20 KB
#define OFF_WT2    (OFF_WT1 + (64u<<10))
#define OFF_POOL   (OFF_WT1 + (128u<<10))
#define OFF_W2T    (OFF_WT1 + (256u<<10))    // 128 KB: W2^T fp16

__device__ __forceinline__ fx4 shfl_xor4(fx4 v, int m) {
    return (fx4){__shfl_xor(v.x, m), __shfl_xor(v.y, m), __shfl_xor(v.z, m), __shfl_xor(v.w, m)};
}

// setup: blocks 0..127 init deg/cnt/pooled (+zero dummy rows of xn, Z);
// 128..143 cvtw (W2->W2T fp16); 144..173 twt (conv weight transpose)
__global__ __launch_bounds__(256) void k_setup(int* deg, int* cnt, float* pooled,
                                               const float* __restrict__ w1, const float* __restrict__ w2,
                                               float* __restrict__ wt1, float* __restrict__ wt2,
                                               const float* __restrict__ gw2, _Float16* __restrict__ w2t,
                                               unsigned* __restrict__ xnz, unsigned* __restrict__ zz) {
    __shared__ float tl[64][65];
    int blk = blockIdx.x, t = threadIdx.x;
    if (blk < 128) {
        int i = blk * 256 + t;
        if (i < NN) { deg[i] = 1; cnt[i] = 0; }   // deg starts at 1 (self-loop)
        if (i < B_ * HID) pooled[i] = 0.f;
        if (blk == 0 && t < 16) xnz[t] = 0u;      // xn dummy row NN (64 B fp16)
        if (blk == 1 && t < 128) zz[t] = 0u;      // Z dummy row NN (512 B)
    } else if (blk < 144) {
        int bb = blk - 128;
        int bx = bb & 3, by = bb >> 2;            // k-tile, n-tile
        #pragma unroll
        for (int it = 0; it < 16; it++) {
            int idx = it * 256 + t;
            int r = idx >> 6, c = idx & 63;
            tl[r][c] = gw2[(size_t)(bx * 64 + r) * 256 + by * 64 + c];
        }
        __syncthreads();
        #pragma unroll
        for (int it = 0; it < 16; it++) {
            int idx = it * 256 + t;
            int r = idx >> 6, c = idx & 63;
            w2t[(size_t)(by * 64 + r) * 256 + bx * 64 + c] = (_Float16)tl[c][r];
        }
    } else {
        int i = (blk - 144) * 256 + t;
        if (i < 16 * 64 * 5) {
            int co = i & 15; int r = i >> 4; int k = r % 5; int ci = r / 5;
            wt1[i] = w1[(co * 64 + ci) * 5 + k];
        }
        int j = i - 16 * 64 * 5;
        if (j >= 0 && j < 32 * 16 * 5) {
            int co = j & 31; int r = j >> 5; int k = r % 5; int ci = r / 5;
            wt2[j] = w2[(co * 16 + ci) * 5 + k];
        }
    }
}

// scan over PADDED degrees ((deg+7)&~7); emits dinv = rsqrt(real deg), dinv[NN]=0.
__global__ __launch_bounds__(1024) void k_scan(const int* __restrict__ deg, int* __restrict__ indptr,
                                               float* __restrict__ dinv) {
    __shared__ int wsum[16];
    int tid = threadIdx.x;
    int lane = tid & 63, w = tid >> 6;
    int base = tid * 32;
    int loc[32]; int s = 0;
    #pragma unroll
    for (int j = 0; j < 32; j++) {
        int d = deg[base + j];
        dinv[base + j] = rsqrtf((float)d);
        loc[j] = d;
        s += (d + 7) & ~7;
    }
    int v = s;                       // inclusive wave scan
    #pragma unroll
    for (int off = 1; off < 64; off <<= 1) {
        int t = __shfl_up(v, off);
        if (lane >= off) v += t;
    }
    if (lane == 63) wsum[w] = v;
    __syncthreads();
    int woff = 0;
    #pragma unroll
    for (int i = 0; i < 16; i++) { int t = wsum[i]; if (i < w) woff += t; }
    int run = woff + v - s;          // exclusive prefix for this thread
    #pragma unroll
    for (int j = 0; j < 32; j++) { indptr[base + j] = run; run += (loc[j] + 7) & ~7; }
    if (tid == 1023) { indptr[NN] = run; dinv[NN] = 0.f; }
}

// FUSED conv1(MFMA implicit GEMM) + count.
#define LDX 72
__global__ __launch_bounds__(256) void k_c1cnt(const float* __restrict__ x, const float* __restrict__ wt1,
                                               const float* __restrict__ b1, float* __restrict__ h1,
                                               const int* __restrict__ ei, int* __restrict__ deg) {
    int blk = blockIdx.x;
    int tid = threadIdx.x;
    if (blk >= 512) {
        int t = (blk - 512) * 256 + tid;   // < NE/4
        int4 d4 = *(const int4*)&ei[NE + 4 * t];
        atomicAdd(&deg[d4.x], 1);
        atomicAdd(&deg[d4.y], 1);
        atomicAdd(&deg[d4.z], 1);
        atomicAdd(&deg[d4.w], 1);
        return;
    }
    __shared__ _Float16 xs[260 * LDX];   // xs[j][ci-swizzled], j = t+2
    __shared__ _Float16 wl[16 * 328];    // wl[co][K], K = kk*64+ci
    __shared__ float ps2[128 * 17];      // pooled out bounce [t1][co]
    int tile = blk & 7;
    int b = blk >> 3;
    int t0 = tile * 256;
    const float* xb = x + ((size_t)b * CIN) * T_ + t0;
    {   // interior cols: lane f covers t 4f..4f+3 of row ci=r -> transposed write
        int f = tid & 63, r0 = tid >> 6;
        #pragma unroll
        for (int it = 0; it < 16; it++) {
            int r = r0 + 4 * it;                       // ci
            fx4 v = *(const fx4*)&xb[(size_t)r * T_ + f * 4];
            #pragma unroll
            for (int q = 0; q < 4; q++) {
                int j = 2 + f * 4 + q;
                xs[j * LDX + ((((r >> 3) ^ (j >> 3)) & 7) << 3) + (r & 7)] = (_Float16)v[q];
            }
        }
        // halo j in {0,1,258,259} (sw(j)=0 there): 1 value per thread
        int r = tid >> 2, c = tid & 3;
        int off = (c < 2) ? (c - 2) : (254 + c);
        int gt = t0 + off;
        float v = 0.f;
        if (gt >= 0 && gt < T_) v = xb[(size_t)r * T_ + off];
        xs[(off + 2) * LDX + r] = (_Float16)v;
        // weights: wl[co][K=kk*64+ci] <- wt1[(ci*5+kk)*16+co]
        for (int i = tid; i < 5120; i += 256) {
            int K = i >> 4, co = i & 15;
            int kk = K >> 6, ci = K & 63;
            wl[co * 328 + K] = (_Float16)wt1[(ci * 5 + kk) * 16 + co];
        }
    }
    __syncthreads();
    int wv = tid >> 6, lane = tid & 63;
    int l15 = lane & 15, g = lane >> 4;
    fx4 acc[4];
    #pragma unroll
    for (int m = 0; m < 4; m++) acc[m] = (fx4){0.f, 0.f, 0.f, 0.f};
    #pragma unroll
    for (int ks = 0; ks < 10; ks++) {
        int kk = ks >> 1;
        int cb = (ks & 1) * 4 + g;                  // ci 8-block index 0..7
        hx8 bf = *(const hx8*)&wl[l15 * 328 + ks * 32 + g * 8];
        #pragma unroll
        for (int m = 0; m < 4; m++) {
            int j = wv * 64 + m * 16 + l15 + kk;    // A row (t + kk), +2-2 folded
            hx8 af = *(const hx8*)&xs[j * LDX + ((((j >> 3) & 7) ^ cb) << 3)];
            acc[m] = __builtin_amdgcn_mfma_f32_16x16x32_f16(af, bf, acc[m], 0, 0, 0);
        }
    }
    // bias + relu + pool2 in-register: C rows g*4+r pair up within the lane
    float bv = b1[l15];
    #pragma unroll
    for (int m = 0; m < 4; m++) {
        int t1b = wv * 32 + m * 8 + g * 2;
        float a0 = fmaxf(acc[m][0] + bv, 0.f);
        float a1 = fmaxf(acc[m][1] + bv, 0.f);
        float a2 = fmaxf(acc[m][2] + bv, 0.f);
        float a3 = fmaxf(acc[m][3] + bv, 0.f);
        ps2[t1b * 17 + l15] = fmaxf(a0, a1);
        ps2[(t1b + 1) * 17 + l15] = fmaxf(a2, a3);
    }
    __syncthreads();
    for (int idx = tid; idx < 2048; idx += 256) {
        int t1 = idx & 127, co = idx >> 7;
        h1[(b * C1 + co) * T1 + tile * 128 + t1] = ps2[t1 * 17 + co];
    }
}

// FUSED conv2 + range-partitioned fill.
// Blocks 0..255: conv2 (tile=blk&3, b=blk>>2) -> xn fp16 (ps stride 33: no
//   bank conflicts).
// Blocks 256..1343: fill, j=blk-256, range g=j&7 (XCD-affine: 256%8==0),
//   slice i=j>>3 (0..135). Each block streams its edge slice (src+dst int4)
//   and handles only dests with d>>12==g -> each 280 KB csrc range and its
//   cnt range written by ONE XCD (no cross-XCD line bouncing). Self-loops and
//   pad sentinels partitioned the same way.
__global__ __launch_bounds__(256) void k_c2fill(const float* __restrict__ h1, const float* __restrict__ wt2,
                                                const float* __restrict__ b2, _Float16* __restrict__ xn,
                                                const int* __restrict__ ei, const int* __restrict__ deg,
                                                const int* __restrict__ indptr, int* __restrict__ cnt,
                                                int* __restrict__ csrc) {
    int blk = blockIdx.x;
    int tid = threadIdx.x;
    if (blk >= 256) {
        int j = blk - 256;           // 0..1087
        int g = j & 7, i = j >> 3;   // dest range, edge slice
        int q0 = i * 964;
        int q1 = (q0 + 964 < NE / 4) ? (q0 + 964) : (NE / 4);
        for (int q = q0 + tid; q < q1; q += 256) {
            int4 s4 = *(const int4*)&ei[4 * q];
            int4 d4 = *(const int4*)&ei[NE + 4 * q];
            if ((d4.x >> 12) == g) { int p = indptr[d4.x] + atomicAdd(&cnt[d4.x], 1); csrc[p] = s4.x; }
            if ((d4.y >> 12) == g) { int p = indptr[d4.y] + atomicAdd(&cnt[d4.y], 1); csrc[p] = s4.y; }
            if ((d4.z >> 12) == g) { int p = indptr[d4.z] + atomicAdd(&cnt[d4.z], 1); csrc[p] = s4.z; }
            if ((d4.w >> 12) == g) { int p = indptr[d4.w] + atomicAdd(&cnt[d4.w], 1); csrc[p] = s4.w; }
        }
        // self-loops + pad sentinels for this slice's nodes in range g
        int n0 = i * 241;
        int n1 = (n0 + 241 < NN) ? (n0 + 241) : NN;
        for (int n = n0 + tid; n < n1; n += 256) {
            if ((n >> 12) == g) {
                int base = indptr[n];
                int p = base + atomicAdd(&cnt[n], 1);
                csrc[p] = n;
                int dd = deg[n], dp = (dd + 7) & ~7;
                for (int k = dd; k < dp; k++) csrc[base + k] = NN;
            }
        }
        return;
    }
    __shared__ float xs[16][260];
    __shared__ float ps[128 * 33];
    int tile = blk & 3;
    int b = blk >> 2;
    int t0 = tile * 256;
    float acc[32];
    #pragma unroll
    for (int i = 0; i < 32; i++) acc[i] = 0.f;
    for (int idx = tid; idx < 16 * 260; idx += 256) {
        int r = idx / 260, c = idx % 260;
        int gt = t0 + c - 2;
        float v = 0.f;
        if (gt >= 0 && gt < T1) v = h1[(b * C1 + r) * T1 + gt];
        xs[r][c] = v;
    }
    __syncthreads();
    for (int ci = 0; ci < 16; ci++) {
        float xv[5];
        #pragma unroll
        for (int j = 0; j < 5; j++) xv[j] = xs[ci][tid + j];
        const float* wp = wt2 + (ci * 5) * 32;
        #pragma unroll
        for (int k = 0; k < 5; k++) {
            #pragma unroll
            for (int co = 0; co < 32; co++)
                acc[co] = fmaf(xv[k], wp[k * 32 + co], acc[co]);
        }
    }
    #pragma unroll
    for (int co = 0; co < 32; co++) {
        float a = fmaxf(acc[co] + b2[co], 0.f);
        float o = fmaxf(a, __shfl_xor(a, 1));
        if ((tid & 1) == 0) ps[(tid >> 1) * 33 + co] = o;
    }
    __syncthreads();
    size_t base = ((size_t)b * T2 + tile * 128) * 32;
    for (int idx = tid; idx < 128 * 16; idx += 256) {
        int t1 = idx >> 4, co = (idx & 15) * 2;
        hx2 h;
        h.x = (_Float16)ps[t1 * 33 + co];
        h.y = (_Float16)ps[t1 * 33 + co + 1];
        *(hx2*)&xn[base + t1 * 32 + co] = h;
    }
}

#define ACC4(v, m) \
    acc.x = fmaf((float)v[0], m, acc.x); acc.y = fmaf((float)v[1], m, acc.y); \
    acc.z = fmaf((float)v[2], m, acc.z); acc.w = fmaf((float)v[3], m, acc.w);

// agg1: y1[n,:] = sum_e dinv[s]*dinv[n] * xn[s,:]; xn fp16 (2 MB, L2-resident).
// Wave per node: 8 edge-slots x 8 lanes x hx4, shfl reduce.
__global__ __launch_bounds__(256) void k_agg32(const _Float16* __restrict__ xn, const int* __restrict__ indptr,
                                               const int* __restrict__ csrc, const float* __restrict__ dinv,
                                               float* __restrict__ y1) {
    int lane = threadIdx.x & 63;
    int n = blockIdx.x * 4 + (threadIdx.x >> 6);
    int eg = lane >> 3, fi = lane & 7;
    int beg = indptr[n];
    int cnt8 = indptr[n + 1] - beg;     // multiple of 8
    float dn = dinv[n];
    const int* cs = csrc + beg;
    fx4 acc = (fx4){0.f, 0.f, 0.f, 0.f};
    for (int i = 0; i < cnt8; i += 8) {
        int s = cs[i + eg];
        float m = dinv[s] * dn;
        hx4 v = *(const hx4*)&xn[(size_t)s * 32 + fi * 4];
        ACC4(v, m)
    }
    acc += shfl_xor4(acc, 8);
    acc += shfl_xor4(acc, 16);
    acc += shfl_xor4(acc, 32);
    if (lane < 8) *(fx4*)&y1[(size_t)n * 32 + fi * 4] = acc;
}

// gemm1: H[N,256] = fp16( relu(y1[N,32] @ W1[32,256] + b1) ); 64-row tiles.
__global__ __launch_bounds__(256) void k_gemm1(const float* __restrict__ A, const float* __restrict__ W,
                                               const float* __restrict__ bias, _Float16* __restrict__ H) {
    __shared__ __align__(16) float xT[32 * 68];   // [k][r], 64 rows + pad
    __shared__ __align__(16) float wl[32 * 256];
    int tid = threadIdx.x;
    int ty = tid >> 4, tx = tid & 15;
    int rows0 = blockIdx.x * 64;
    int kq = tid & 7, rs = tid >> 3;              // staging coords (rs 0..31)
    {
        fx4 v0 = *(const fx4*)&A[(size_t)(rows0 + rs) * 32 + kq * 4];
        fx4 v1 = *(const fx4*)&A[(size_t)(rows0 + rs + 32) * 32 + kq * 4];
        #pragma unroll
        for (int i = 0; i < 4; i++) {
            xT[(kq * 4 + i) * 68 + rs]      = v0[i];
            xT[(kq * 4 + i) * 68 + rs + 32] = v1[i];
        }
    }
    #pragma unroll
    for (int m = 0; m < 8; m++)
        *(fx4*)&wl[m * 1024 + tid * 4] = *(const fx4*)&W[(size_t)(m * 1024 + tid * 4)];
    __syncthreads();

    fx4 c[4][4];
    #pragma unroll
    for (int i = 0; i < 4; i++)
        #pragma unroll
        for (int j = 0; j < 4; j++) c[i][j] = (fx4){0.f, 0.f, 0.f, 0.f};

    #pragma unroll 8
    for (int kk = 0; kk < 32; kk++) {
        fx4 xa = *(const fx4*)&xT[kk * 68 + ty * 4];
        fx4 w[4];
        w[0] = *(const fx4*)&wl[kk * 256 + tx * 8];
        w[1] = *(const fx4*)&wl[kk * 256 + tx * 8 + 4];
        w[2] = *(const fx4*)&wl[kk * 256 + tx * 8 + 128];
        w[3] = *(const fx4*)&wl[kk * 256 + tx * 8 + 132];
        #pragma unroll
        for (int j = 0; j < 4; j++) {
            c[0][j] += xa.x * w[j];
            c[1][j] += xa.y * w[j];
            c[2][j] += xa.z * w[j];
            c[3][j] += xa.w * w[j];
        }
    }
    fx4 bb[4];
    bb[0] = *(const fx4*)&bias[tx * 8];
    bb[1] = *(const fx4*)&bias[tx * 8 + 4];
    bb[2] = *(const fx4*)&bias[tx * 8 + 128];
    bb[3] = *(const fx4*)&bias[tx * 8 + 132];
    #pragma unroll
    for (int i = 0; i < 4; i++) {
        int r = rows0 + ty * 4 + i;
        fx4 v0 = c[i][0] + bb[0], v1 = c[i][1] + bb[1];
        fx4 v2 = c[i][2] + bb[2], v3 = c[i][3] + bb[3];
        hx8 h0, h1;
        #pragma unroll
        for (int q = 0; q < 4; q++) {
            h0[q]     = (_Float16)fmaxf(v0[q], 0.f);
            h0[q + 4] = (_Float16)fmaxf(v1[q], 0.f);
            h1[q]     = (_Float16)fmaxf(v2[q], 0.f);
            h1[q + 4] = (_Float16)fmaxf(v3[q], 0.f);
        }
        *(hx8*)&H[(size_t)r * 256 + tx * 8]       = h0;
        *(hx8*)&H[(size_t)r * 256 + tx * 8 + 128] = h1;
    }
}

// gemm2 MFMA: Z[N,256] = fp16( H[N,256] @ W2 ), 128x128 tile, BK=64, dbuf LDS.
#define LDH 72
__global__ __launch_bounds__(256, 2) void k_gemm2m(const _Float16* __restrict__ A,
                                                   const _Float16* __restrict__ Bt,
                                                   _Float16* __restrict__ Z) {
    __shared__ __align__(16) _Float16 As[2][128 * LDH];
    __shared__ __align__(16) _Float16 Bs[2][128 * LDH];
    int tid = threadIdx.x;
    int lane = tid & 63, wid = tid >> 6;
    int wm = wid >> 1, wn = wid & 1;
    int row0 = blockIdx.x * 128, col0 = blockIdx.y * 128;
    int l15 = lane & 15, g = lane >> 4;
    int sr = tid >> 3, sc = tid & 7;

    fx4 acc[4][4];
    #pragma unroll
    for (int m = 0; m < 4; m++)
        #pragma unroll
        for (int n = 0; n < 4; n++) acc[m][n] = (fx4){0.f, 0.f, 0.f, 0.f};

    uint4 ga[4], gb[4];
    #pragma unroll
    for (int it = 0; it < 4; it++) {
        ga[it] = *(const uint4*)&A[(size_t)(row0 + sr + 32 * it) * 256 + sc * 8];
        gb[it] = *(const uint4*)&Bt[(size_t)(col0 + sr + 32 * it) * 256 + sc * 8];
    }
    #pragma unroll
    for (int it = 0; it < 4; it++) {
        *(uint4*)&As[0][(sr + 32 * it) * LDH + sc * 8] = ga[it];
        *(uint4*)&Bs[0][(sr + 32 * it) * LDH + sc * 8] = gb[it];
    }
    __syncthreads();

    int cur = 0;
    for (int t = 0; t < 4; t++) {
        if (t < 3) {
            int k0 = (t + 1) * 64;
            #pragma unroll
            for (int it = 0; it < 4; it++) {
                ga[it] = *(const uint4*)&A[(size_t)(row0 + sr + 32 * it) * 256 + k0 + sc * 8];
                gb[it] = *(const uint4*)&Bt[(size_t)(col0 + sr + 32 * it) * 256 + k0 + sc * 8];
            }
        }
        const _Float16* ap = As[cur];
        const _Float16* bp = Bs[cur];
        hx8 af[4][2], bf[4][2];
        #pragma unroll
        for (int m = 0; m < 4; m++)
            #pragma unroll
            for (int ks = 0; ks < 2; ks++)
                af[m][ks] = *(const hx8*)&ap[(wm * 64 + m * 16 + l15) * LDH + ks * 32 + g * 8];
        #pragma unroll
        for (int n = 0; n < 4; n++)
            #pragma unroll
            for (int ks = 0; ks < 2; ks++)
                bf[n][ks] = *(const hx8*)&bp[(wn * 64 + n * 16 + l15) * LDH + ks * 32 + g * 8];
        #pragma unroll
        for (int m = 0; m < 4; m++)
            #pragma unroll
            for (int n = 0; n < 4; n++) {
                acc[m][n] = __builtin_amdgcn_mfma_f32_16x16x32_f16(af[m][0], bf[n][0], acc[m][n], 0, 0, 0);
                acc[m][n] = __builtin_amdgcn_mfma_f32_16x16x32_f16(af[m][1], bf[n][1], acc[m][n], 0, 0, 0);
            }
        if (t < 3) {
            #pragma unroll
            for (int it = 0; it < 4; it++) {
                *(uint4*)&As[cur ^ 1][(sr + 32 * it) * LDH + sc * 8] = ga[it];
                *(uint4*)&Bs[cur ^ 1][(sr + 32 * it) * LDH + sc * 8] = gb[it];
            }
        }
        __syncthreads();
        cur ^= 1;
    }

    #pragma unroll
    for (int m = 0; m < 4; m++)
        #pragma unroll
        for (int n = 0; n < 4; n++) {
            int cc = col0 + wn * 64 + n * 16 + l15;
            #pragma unroll
            for (int r = 0; r < 4; r++) {
                int rr = row0 + wm * 64 + m * 16 + g * 4 + r;
                Z[(size_t)rr * 256 + cc] = (_Float16)acc[m][n][r];
            }
        }
}

// agg2 + mean fused: wave handles 8 consecutive nodes sequentially, running
// sum of relu(acc + b2) in registers; block (4 waves x 8 nodes = 32 nodes,
// one batch) LDS-reduces, ONE atomic per lane. Full wave per row (64 lanes x
// hx4 = 512 B), 8 rows in flight per iter.
__global__ __launch_bounds__(256) void k_aggm(const _Float16* __restrict__ Z, const int* __restrict__ indptr,
                                              const int* __restrict__ csrc, const float* __restrict__ dinv,
                                              const float* __restrict__ bias, float* __restrict__ pooled) {
    __shared__ float ps[4][256];
    int tid = threadIdx.x;
    int wid = tid >> 6, lane = tid & 63;
    int n0 = blockIdx.x * 32 + wid * 8;
    fx4 bb = *(const fx4*)&bias[lane * 4];
    fx4 racc = (fx4){0.f, 0.f, 0.f, 0.f};
    #pragma unroll 1
    for (int u = 0; u < 8; u++) {
        int n = n0 + u;
        int beg = indptr[n];
        int cnt8 = indptr[n + 1] - beg;     // multiple of 8 (padded lists)
        float dn = dinv[n];
        const int* cs = csrc + beg;
        fx4 acc = (fx4){0.f, 0.f, 0.f, 0.f};
        for (int i = 0; i < cnt8; i += 8) {
            int4 ia = *(const int4*)&cs[i];
            int4 ib = *(const int4*)&cs[i + 4];
            float m0 = dinv[ia.x] * dn, m1 = dinv[ia.y] * dn;
            float m2 = dinv[ia.z] * dn, m3 = dinv[ia.w] * dn;
            float m4 = dinv[ib.x] * dn, m5 = dinv[ib.y] * dn;
            float m6 = dinv[ib.z] * dn, m7 = dinv[ib.w] * dn;
            hx4 v0 = *(const hx4*)&Z[(size_t)ia.x * 256 + lane * 4];
            hx4 v1 = *(const hx4*)&Z[(size_t)ia.y * 256 + lane * 4];
            hx4 v2 = *(const hx4*)&Z[(size_t)ia.z * 256 + lane * 4];
            hx4 v3 = *(const hx4*)&Z[(size_t)ia.w * 256 + lane * 4];
            hx4 v4 = *(const hx4*)&Z[(size_t)ib.x * 256 + lane * 4];
            hx4 v5 = *(const hx4*)&Z[(size_t)ib.y * 256 + lane * 4];
            hx4 v6 = *(const hx4*)&Z[(size_t)ib.z * 256 + lane * 4];
            hx4 v7 = *(const hx4*)&Z[(size_t)ib.w * 256 + lane * 4];
            ACC4(v0, m0)
            ACC4(v1, m1)
            ACC4(v2, m2)
            ACC4(v3, m3)
            ACC4(v4, m4)
            ACC4(v5, m5)
            ACC4(v6, m6)
            ACC4(v7, m7)
        }
        acc += bb;
        racc.x += fmaxf(acc.x, 0.f); racc.y += fmaxf(acc.y, 0.f);
        racc.z += fmaxf(acc.z, 0.f); racc.w += fmaxf(acc.w, 0.f);
    }
    *(fx4*)&ps[wid][lane * 4] = racc;
    __syncthreads();
    float s = ps[0][tid] + ps[1][tid] + ps[2][tid] + ps[3][tid];
    atomicAdd(&pooled[(blockIdx.x >> 4) * 256 + tid], s * (1.f / 512.f));
}

__global__ __launch_bounds__(64) void k_cls(const float* __restrict__ pooled, const float* __restrict__ cw,
                                            const float* __restrict__ cb, float* __restrict__ outp) {
    int b = blockIdx.x, lane = threadIdx.x;
    float po[10];
    #pragma unroll
    for (int o = 0; o < 10; o++) po[o] = 0.f;
    #pragma unroll
    for (int m = 0; m < 4; m++) {
        int hh = lane + m * 64;
        float ph = pooled[b * HID + hh];
        #pragma unroll
        for (int o = 0; o < 10; o++) po[o] = fmaf(ph, cw[hh * 10 + o], po[o]);
    }
    #pragma unroll
    for (int off = 32; off >= 1; off >>= 1) {
        #pragma unroll
        for (int o = 0; o < 10; o++) po[o] += __shfl_down(po[o], off);
    }
    if (lane == 0) {
        #pragma unroll
        for (int o = 0; o < 10; o++) outp[b * 10 + o] = po[o] + cb[o];
    }
}

extern "C" void kernel_launch(void* const* d_in, const int* in_sizes, int n_in,
                              void* d_out, int out_size, void* d_ws, size_t ws_size,
                              hipStream_t stream) {
    const float* x   = (const float*)d_in[0];
    const int*   ei  = (const int*)d_in[1];
    const float* w1  = (const float*)d_in[2];
    const float* b1  = (const float*)d_in[3];
    const float* w2  = (const float*)d_in[4];
    const float* b2  = (const float*)d_in[5];
    const float* g1w = (const float*)d_in[6];
    const float* g1b = (const float*)d_in[7];
    const float* g2w = (const float*)d_in[8];
    const float* g2b = (const float*)d_in[9];
    const float* cw  = (const float*)d_in[10];
    const float* cb  = (const float*)d_in[11];
    float* out = (float*)d_out;
    char* ws = (char*)d_ws;

    _Float16*       H      = (_Float16*)(ws + OFF_H);
    _Float16*       Z      = (_Float16*)(ws + OFF_Z);
    float*          h1     = (float*)(ws + OFF_H1);
    _Float16*       xn     = (_Float16*)(ws + OFF_XN);
    float*          y1     = (float*)(ws + OFF_Y1);
    int*            deg    = (int*)(ws + OFF_DEG);
    int*            indptr = (int*)(ws + OFF_INDPTR);
    int*            cnt    = (int*)(ws + OFF_CNT);
    float*          dinv   = (float*)(ws + OFF_DINV);
    int*            csrc   = (int*)(ws + OFF_CSRC);
    float*          wt1    = (float*)(ws + OFF_WT1);
    float*          wt2    = (float*)(ws + OFF_WT2);
    float*          pooled = (float*)(ws + OFF_POOL);
    _Float16*       w2t    = (_Float16*)(ws + OFF_W2T);
    unsigned*       xnz    = (unsigned*)(xn + (size_t)NN * 32);      // dummy row NN of xn
    unsigned*       zz     = (unsigned*)(Z + (size_t)NN * 256);      // dummy row NN of Z

    k_setup <<<174, 256, 0, stream>>>(deg, cnt, pooled, w1, w2, wt1, wt2, g2w, w2t, xnz, zz);
    k_c1cnt <<<1024, 256, 0, stream>>>(x, wt1, b1, h1, ei, deg);             // conv1(MFMA) || count
    k_scan  <<<1, 1024, 0, stream>>>(deg, indptr, dinv);
    k_c2fill<<<1344, 256, 0, stream>>>(h1, wt2, b2, xn, ei, deg, indptr, cnt, csrc);  // conv2 || fill(XCD-ranged)
    k_agg32 <<<8192, 256, 0, stream>>>(xn, indptr, csrc, dinv, y1);          // y1 = A^ . X (32-wide)
    k_gemm1 <<<512, 256, 0, stream>>>(y1, g1w, g1b, H);                      // H = fp16(relu(y1@W1+b1))
    k_gemm2m<<<dim3(256, 2), 256, 0, stream>>>(H, w2t, Z);                   // Z = fp16(H@W2)
    k_aggm  <<<1024, 256, 0, stream>>>(Z, indptr, csrc, dinv, g2b, pooled);  // pooled += relu(A^ . Z + b2)/512
    k_cls   <<<64, 64, 0, stream>>>(pooled, cw, cb, out);
}

// Round 15
// 153.640 us; speedup vs baseline: 1.5700x; 1.0813x over previous
//
#include <hip/hip_runtime.h>

#define B_ 64
#define CIN 64
#define T_ 2048
#define C1 16
#define T1 1024
#define C2 32
#define T2 512
#define NN 32768
#define HID 256
#define OUTD 10
#define NE 524288
#define NTOT (NE + NN)          // 557056

typedef __attribute__((ext_vector_type(4))) float fx4;
typedef __attribute__((ext_vector_type(2))) float fx2f;
typedef __attribute__((ext_vector_type(8))) _Float16 hx8;
typedef __attribute__((ext_vector_type(4))) _Float16 hx4;
typedef __attribute__((ext_vector_type(2))) _Float16 hx2;

// ---- workspace byte offsets (ws proven >= 75 MB) ----
#define OFF_H      (0ull)                    // 16 MB: H fp16 [N][256]
#define OFF_Z      (16ull<<20)               // 8 MB + 256B: Z fp8 [N+1][256] (row NN = zero dummy)
#define OFF_H1     (33ull<<20)               // 4 MB: conv1 out
#define OFF_XN     (37ull<<20)               // 2 MB + 64B: xn fp16 [N+1][32] (row NN = zero dummy)
#define OFF_Y1     (42ull<<20)               // 4 MB: agg1 out fp32 [N][32]
#define OFF_DEG    (46ull<<20)               // 128 KB int
#define OFF_INDPTR ((46ull<<20) + (256u<<10))
#define OFF_CNT    ((46ull<<20) + (512u<<10))
#define OFF_DINV   ((46ull<<20) + (768u<<10))   // [N+1] floats
#define OFF_CSRC   (47ull<<20)               // padded CSR src, cap 3.25 MB
#define OFF_WT1    (51ull<<20)               // 20 KB
#define OFF_WT2    (OFF_WT1 + (64u<<10))
#define OFF_POOL   (OFF_WT1 + (128u<<10))
#define OFF_W2T    (OFF_WT1 + (256u<<10))    // 128 KB: W2^T fp16

__device__ __forceinline__ fx4 shfl_xor4(fx4 v, int m) {
    return (fx4){__shfl_xor(v.x, m), __shfl_xor(v.y, m), __shfl_xor(v.z, m), __shfl_xor(v.w, m)};
}

// setup: blocks 0..127 init deg/cnt/pooled (+zero dummy rows of xn, Z);
// 128..143 cvtw (W2->W2T fp16); 144..173 twt (conv weight transpose)
__global__ __launch_bounds__(256) void k_setup(int* deg, int* cnt, float* pooled,
                                               const float* __restrict__ w1, const float* __restrict__ w2,
                                               float* __restrict__ wt1, float* __restrict__ wt2,
                                               const float* __restrict__ gw2, _Float16* __restrict__ w2t,
                                               unsigned* __restrict__ xnz, unsigned* __restrict__ zz) {
    __shared__ float tl[64][65];
    int blk = blockIdx.x, t = threadIdx.x;
    if (blk < 128) {
        int i = blk * 256 + t;
        if (i < NN) { deg[i] = 1; cnt[i] = 0; }   // deg starts at 1 (self-loop)
        if (i < B_ * HID) pooled[i] = 0.f;
        if (blk == 0 && t < 16) xnz[t] = 0u;      // xn dummy row NN (64 B fp16)
        if (blk == 1 && t < 64) zz[t] = 0u;       // Z dummy row NN (256 B fp8)
    } else if (blk < 144) {
        int bb = blk - 128;
        int bx = bb & 3, by = bb >> 2;            // k-tile, n-tile
        #pragma unroll
        for (int it = 0; it < 16; it++) {
            int idx = it * 256 + t;
            int r = idx >> 6, c = idx & 63;
            tl[r][c] = gw2[(size_t)(bx * 64 + r) * 256 + by * 64 + c];
        }
        __syncthreads();
        #pragma unroll
        for (int it = 0; it < 16; it++) {
            int idx = it * 256 + t;
            int r = idx >> 6, c = idx & 63;
            w2t[(size_t)(by * 64 + r) * 256 + bx * 64 + c] = (_Float16)tl[c][r];
        }
    } else {
        int i = (blk - 144) * 256 + t;
        if (i < 16 * 64 * 5) {
            int co = i & 15; int r = i >> 4; int k = r % 5; int ci = r / 5;
            wt1[i] = w1[(co * 64 + ci) * 5 + k];
        }
        int j = i - 16 * 64 * 5;
        if (j >= 0 && j < 32 * 16 * 5) {
            int co = j & 31; int r = j >> 5; int k = r % 5; int ci = r / 5;
            wt2[j] = w2[(co * 16 + ci) * 5 + k];
        }
    }
}

// scan over PADDED degrees ((deg+7)&~7); emits dinv = rsqrt(real deg), dinv[NN]=0.
__global__ __launch_bounds__(1024) void k_scan(const int* __restrict__ deg, int* __restrict__ indptr,
                                               float* __restrict__ dinv) {
    __shared__ int wsum[16];
    int tid = threadIdx.x;
    int lane = tid & 63, w = tid >> 6;
    int base = tid * 32;
    int loc[32]; int s = 0;
    #pragma unroll
    for (int j = 0; j < 32; j++) {
        int d = deg[base + j];
        dinv[base + j] = rsqrtf((float)d);
        loc[j] = d;
        s += (d + 7) & ~7;
    }
    int v = s;                       // inclusive wave scan
    #pragma unroll
    for (int off = 1; off < 64; off <<= 1) {
        int t = __shfl_up(v, off);
        if (lane >= off) v += t;
    }
    if (lane == 63) wsum[w] = v;
    __syncthreads();
    int woff = 0;
    #pragma unroll
    for (int i = 0; i < 16; i++) { int t = wsum[i]; if (i < w) woff += t; }
    int run = woff + v - s;          // exclusive prefix for this thread
    #pragma unroll
    for (int j = 0; j < 32; j++) { indptr[base + j] = run; run += (loc[j] + 7) & ~7; }
    if (tid == 1023) { indptr[NN] = run; dinv[NN] = 0.f; }
}

// FUSED conv1(MFMA implicit GEMM) + count.
#define LDX 72
__global__ __launch_bounds__(256) void k_c1cnt(const float* __restrict__ x, const float* __restrict__ wt1,
                                               const float* __restrict__ b1, float* __restrict__ h1,
                                               const int* __restrict__ ei, int* __restrict__ deg) {
    int blk = blockIdx.x;
    int tid = threadIdx.x;
    if (blk >= 512) {
        int t = (blk - 512) * 256 + tid;   // < NE/4
        int4 d4 = *(const int4*)&ei[NE + 4 * t];
        atomicAdd(&deg[d4.x], 1);
        atomicAdd(&deg[d4.y], 1);
        atomicAdd(&deg[d4.z], 1);
        atomicAdd(&deg[d4.w], 1);
        return;
    }
    __shared__ _Float16 xs[260 * LDX];   // xs[j][ci-swizzled], j = t+2
    __shared__ _Float16 wl[16 * 328];    // wl[co][K], K = kk*64+ci
    __shared__ float ps2[128 * 17];      // pooled out bounce [t1][co]
    int tile = blk & 7;
    int b = blk >> 3;
    int t0 = tile * 256;
    const float* xb = x + ((size_t)b * CIN) * T_ + t0;
    {   // interior cols: lane f covers t 4f..4f+3 of row ci=r -> transposed write
        int f = tid & 63, r0 = tid >> 6;
        #pragma unroll
        for (int it = 0; it < 16; it++) {
            int r = r0 + 4 * it;                       // ci
            fx4 v = *(const fx4*)&xb[(size_t)r * T_ + f * 4];
            #pragma unroll
            for (int q = 0; q < 4; q++) {
                int j = 2 + f * 4 + q;
                xs[j * LDX + ((((r >> 3) ^ (j >> 3)) & 7) << 3) + (r & 7)] = (_Float16)v[q];
            }
        }
        // halo j in {0,1,258,259} (sw(j)=0 there): 1 value per thread
        int r = tid >> 2, c = tid & 3;
        int off = (c < 2) ? (c - 2) : (254 + c);
        int gt = t0 + off;
        float v = 0.f;
        if (gt >= 0 && gt < T_) v = xb[(size_t)r * T_ + off];
        xs[(off + 2) * LDX + r] = (_Float16)v;
        // weights: wl[co][K=kk*64+ci] <- wt1[(ci*5+kk)*16+co]
        for (int i = tid; i < 5120; i += 256) {
            int K = i >> 4, co = i & 15;
            int kk = K >> 6, ci = K & 63;
            wl[co * 328 + K] = (_Float16)wt1[(ci * 5 + kk) * 16 + co];
        }
    }
    __syncthreads();
    int wv = tid >> 6, lane = tid & 63;
    int l15 = lane & 15, g = lane >> 4;
    fx4 acc[4];
    #pragma unroll
    for (int m = 0; m < 4; m++) acc[m] = (fx4){0.f, 0.f, 0.f, 0.f};
    #pragma unroll
    for (int ks = 0; ks < 10; ks++) {
        int kk = ks >> 1;
        int cb = (ks & 1) * 4 + g;                  // ci 8-block index 0..7
        hx8 bf = *(const hx8*)&wl[l15 * 328 + ks * 32 + g * 8];
        #pragma unroll
        for (int m = 0; m < 4; m++) {
            int j = wv * 64 + m * 16 + l15 + kk;    // A row (t + kk), +2-2 folded
            hx8 af = *(const hx8*)&xs[j * LDX + ((((j >> 3) & 7) ^ cb) << 3)];
            acc[m] = __builtin_amdgcn_mfma_f32_16x16x32_f16(af, bf, acc[m], 0, 0, 0);
        }
    }
    // bias + relu + pool2 in-register: C rows g*4+r pair up within the lane
    float bv = b1[l15];
    #pragma unroll
    for (int m = 0; m < 4; m++) {
        int t1b = wv * 32 + m * 8 + g * 2;
        float a0 = fmaxf(acc[m][0] + bv, 0.f);
        float a1 = fmaxf(acc[m][1] + bv, 0.f);
        float a2 = fmaxf(acc[m][2] + bv, 0.f);
        float a3 = fmaxf(acc[m][3] + bv, 0.f);
        ps2[t1b * 17 + l15] = fmaxf(a0, a1);
        ps2[(t1b + 1) * 17 + l15] = fmaxf(a2, a3);
    }
    __syncthreads();
    for (int idx = tid; idx < 2048; idx += 256) {
        int t1 = idx & 127, co = idx >> 7;
        h1[(b * C1 + co) * T1 + tile * 128 + t1] = ps2[t1 * 17 + co];
    }
}

// FUSED conv2 + range-partitioned fill (XCD-affine dest ranges).
__global__ __launch_bounds__(256) void k_c2fill(const float* __restrict__ h1, const float* __restrict__ wt2,
                                                const float* __restrict__ b2, _Float16* __restrict__ xn,
                                                const int* __restrict__ ei, const int* __restrict__ deg,
                                                const int* __restrict__ indptr, int* __restrict__ cnt,
                                                int* __restrict__ csrc) {
    int blk = blockIdx.x;
    int tid = threadIdx.x;
    if (blk >= 256) {
        int j = blk - 256;           // 0..1087
        int g = j & 7, i = j >> 3;   // dest range, edge slice
        int q0 = i * 964;
        int q1 = (q0 + 964 < NE / 4) ? (q0 + 964) : (NE / 4);
        for (int q = q0 + tid; q < q1; q += 256) {
            int4 s4 = *(const int4*)&ei[4 * q];
            int4 d4 = *(const int4*)&ei[NE + 4 * q];
            if ((d4.x >> 12) == g) { int p = indptr[d4.x] + atomicAdd(&cnt[d4.x], 1); csrc[p] = s4.x; }
            if ((d4.y >> 12) == g) { int p = indptr[d4.y] + atomicAdd(&cnt[d4.y], 1); csrc[p] = s4.y; }
            if ((d4.z >> 12) == g) { int p = indptr[d4.z] + atomicAdd(&cnt[d4.z], 1); csrc[p] = s4.z; }
            if ((d4.w >> 12) == g) { int p = indptr[d4.w] + atomicAdd(&cnt[d4.w], 1); csrc[p] = s4.w; }
        }
        // self-loops + pad sentinels for this slice's nodes in range g
        int n0 = i * 241;
        int n1 = (n0 + 241 < NN) ? (n0 + 241) : NN;
        for (int n = n0 + tid; n < n1; n += 256) {
            if ((n >> 12) == g) {
                int base = indptr[n];
                int p = base + atomicAdd(&cnt[n], 1);
                csrc[p] = n;
                int dd = deg[n], dp = (dd + 7) & ~7;
                for (int k = dd; k < dp; k++) csrc[base + k] = NN;
            }
        }
        return;
    }
    __shared__ float xs[16][260];
    __shared__ float ps[128 * 33];
    int tile = blk & 3;
    int b = blk >> 2;
    int t0 = tile * 256;
    float acc[32];
    #pragma unroll
    for (int i = 0; i < 32; i++) acc[i] = 0.f;
    for (int idx = tid; idx < 16 * 260; idx += 256) {
        int r = idx / 260, c = idx % 260;
        int gt = t0 + c - 2;
        float v = 0.f;
        if (gt >= 0 && gt < T1) v = h1[(b * C1 + r) * T1 + gt];
        xs[r][c] = v;
    }
    __syncthreads();
    for (int ci = 0; ci < 16; ci++) {
        float xv[5];
        #pragma unroll
        for (int j = 0; j < 5; j++) xv[j] = xs[ci][tid + j];
        const float* wp = wt2 + (ci * 5) * 32;
        #pragma unroll
        for (int k = 0; k < 5; k++) {
            #pragma unroll
            for (int co = 0; co < 32; co++)
                acc[co] = fmaf(xv[k], wp[k * 32 + co], acc[co]);
        }
    }
    #pragma unroll
    for (int co = 0; co < 32; co++) {
        float a = fmaxf(acc[co] + b2[co], 0.f);
        float o = fmaxf(a, __shfl_xor(a, 1));
        if ((tid & 1) == 0) ps[(tid >> 1) * 33 + co] = o;
    }
    __syncthreads();
    size_t base = ((size_t)b * T2 + tile * 128) * 32;
    for (int idx = tid; idx < 128 * 16; idx += 256) {
        int t1 = idx >> 4, co = (idx & 15) * 2;
        hx2 h;
        h.x = (_Float16)ps[t1 * 33 + co];
        h.y = (_Float16)ps[t1 * 33 + co + 1];
        *(hx2*)&xn[base + t1 * 32 + co] = h;
    }
}

#define ACC4(v, m) \
    acc.x = fmaf((float)v[0], m, acc.x); acc.y = fmaf((float)v[1], m, acc.y); \
    acc.z = fmaf((float)v[2], m, acc.z); acc.w = fmaf((float)v[3], m, acc.w);

// agg1: y1[n,:] = sum_e dinv[s]*dinv[n] * xn[s,:]; xn fp16 (2 MB, L2-resident).
// Wave per node: 8 edge-slots x 8 lanes x hx4, shfl reduce.
__global__ __launch_bounds__(256) void k_agg32(const _Float16* __restrict__ xn, const int* __restrict__ indptr,
                                               const int* __restrict__ csrc, const float* __restrict__ dinv,
                                               float* __restrict__ y1) {
    int lane = threadIdx.x & 63;
    int n = blockIdx.x * 4 + (threadIdx.x >> 6);
    int eg = lane >> 3, fi = lane & 7;
    int beg = indptr[n];
    int cnt8 = indptr[n + 1] - beg;     // multiple of 8
    float dn = dinv[n];
    const int* cs = csrc + beg;
    fx4 acc = (fx4){0.f, 0.f, 0.f, 0.f};
    for (int i = 0; i < cnt8; i += 8) {
        int s = cs[i + eg];
        float m = dinv[s] * dn;
        hx4 v = *(const hx4*)&xn[(size_t)s * 32 + fi * 4];
        ACC4(v, m)
    }
    acc += shfl_xor4(acc, 8);
    acc += shfl_xor4(acc, 16);
    acc += shfl_xor4(acc, 32);
    if (lane < 8) *(fx4*)&y1[(size_t)n * 32 + fi * 4] = acc;
}

// gemm1: H[N,256] = fp16( relu(y1[N,32] @ W1[32,256] + b1) ); 64-row tiles.
__global__ __launch_bounds__(256) void k_gemm1(const float* __restrict__ A, const float* __restrict__ W,
                                               const float* __restrict__ bias, _Float16* __restrict__ H) {
    __shared__ __align__(16) float xT[32 * 68];   // [k][r], 64 rows + pad
    __shared__ __align__(16) float wl[32 * 256];
    int tid = threadIdx.x;
    int ty = tid >> 4, tx = tid & 15;
    int rows0 = blockIdx.x * 64;
    int kq = tid & 7, rs = tid >> 3;              // staging coords (rs 0..31)
    {
        fx4 v0 = *(const fx4*)&A[(size_t)(rows0 + rs) * 32 + kq * 4];
        fx4 v1 = *(const fx4*)&A[(size_t)(rows0 + rs + 32) * 32 + kq * 4];
        #pragma unroll
        for (int i = 0; i < 4; i++) {
            xT[(kq * 4 + i) * 68 + rs]      = v0[i];
            xT[(kq * 4 + i) * 68 + rs + 32] = v1[i];
        }
    }
    #pragma unroll
    for (int m = 0; m < 8; m++)
        *(fx4*)&wl[m * 1024 + tid * 4] = *(const fx4*)&W[(size_t)(m * 1024 + tid * 4)];
    __syncthreads();

    fx4 c[4][4];
    #pragma unroll
    for (int i = 0; i < 4; i++)
        #pragma unroll
        for (int j = 0; j < 4; j++) c[i][j] = (fx4){0.f, 0.f, 0.f, 0.f};

    #pragma unroll 8
    for (int kk = 0; kk < 32; kk++) {
        fx4 xa = *(const fx4*)&xT[kk * 68 + ty * 4];
        fx4 w[4];
        w[0] = *(const fx4*)&wl[kk * 256 + tx * 8];
        w[1] = *(const fx4*)&wl[kk * 256 + tx * 8 + 4];
        w[2] = *(const fx4*)&wl[kk * 256 + tx * 8 + 128];
        w[3] = *(const fx4*)&wl[kk * 256 + tx * 8 + 132];
        #pragma unroll
        for (int j = 0; j < 4; j++) {
            c[0][j] += xa.x * w[j];
            c[1][j] += xa.y * w[j];
            c[2][j] += xa.z * w[j];
            c[3][j] += xa.w * w[j];
        }
    }
    fx4 bb[4];
    bb[0] = *(const fx4*)&bias[tx * 8];
    bb[1] = *(const fx4*)&bias[tx * 8 + 4];
    bb[2] = *(const fx4*)&bias[tx * 8 + 128];
    bb[3] = *(const fx4*)&bias[tx * 8 + 132];
    #pragma unroll
    for (int i = 0; i < 4; i++) {
        int r = rows0 + ty * 4 + i;
        fx4 v0 = c[i][0] + bb[0], v1 = c[i][1] + bb[1];
        fx4 v2 = c[i][2] + bb[2], v3 = c[i][3] + bb[3];
        hx8 h0, h1;
        #pragma unroll
        for (int q = 0; q < 4; q++) {
            h0[q]     = (_Float16)fmaxf(v0[q], 0.f);
            h0[q + 4] = (_Float16)fmaxf(v1[q], 0.f);
            h1[q]     = (_Float16)fmaxf(v2[q], 0.f);
            h1[q + 4] = (_Float16)fmaxf(v3[q], 0.f);
        }
        *(hx8*)&H[(size_t)r * 256 + tx * 8]       = h0;
        *(hx8*)&H[(size_t)r * 256 + tx * 8 + 128] = h1;
    }
}

// gemm2 MFMA: Z[N,256] = fp8( H[N,256] @ W2 ), 128x128 tile, BK=64, dbuf LDS.
// Epilogue converts fp32 acc -> OCP e4m3 via v_cvt_pk_fp8_f32 (byte stores,
// 16 consecutive lanes = 16 consecutive bytes -> coalesced 64B/wave-instr).
#define LDH 72
__global__ __launch_bounds__(256, 2) void k_gemm2m(const _Float16* __restrict__ A,
                                                   const _Float16* __restrict__ Bt,
                                                   unsigned char* __restrict__ Z) {
    __shared__ __align__(16) _Float16 As[2][128 * LDH];
    __shared__ __align__(16) _Float16 Bs[2][128 * LDH];
    int tid = threadIdx.x;
    int lane = tid & 63, wid = tid >> 6;
    int wm = wid >> 1, wn = wid & 1;
    int row0 = blockIdx.x * 128, col0 = blockIdx.y * 128;
    int l15 = lane & 15, g = lane >> 4;
    int sr = tid >> 3, sc = tid & 7;

    fx4 acc[4][4];
    #pragma unroll
    for (int m = 0; m < 4; m++)
        #pragma unroll
        for (int n = 0; n < 4; n++) acc[m][n] = (fx4){0.f, 0.f, 0.f, 0.f};

    uint4 ga[4], gb[4];
    #pragma unroll
    for (int it = 0; it < 4; it++) {
        ga[it] = *(const uint4*)&A[(size_t)(row0 + sr + 32 * it) * 256 + sc * 8];
        gb[it] = *(const uint4*)&Bt[(size_t)(col0 + sr + 32 * it) * 256 + sc * 8];
    }
    #pragma unroll
    for (int it = 0; it < 4; it++) {
        *(uint4*)&As[0][(sr + 32 * it) * LDH + sc * 8] = ga[it];
        *(uint4*)&Bs[0][(sr + 32 * it) * LDH + sc * 8] = gb[it];
    }
    __syncthreads();

    int cur = 0;
    for (int t = 0; t < 4; t++) {
        if (t < 3) {
            int k0 = (t + 1) * 64;
            #pragma unroll
            for (int it = 0; it < 4; it++) {
                ga[it] = *(const uint4*)&A[(size_t)(row0 + sr + 32 * it) * 256 + k0 + sc * 8];
                gb[it] = *(const uint4*)&Bt[(size_t)(col0 + sr + 32 * it) * 256 + k0 + sc * 8];
            }
        }
        const _Float16* ap = As[cur];
        const _Float16* bp = Bs[cur];
        hx8 af[4][2], bf[4][2];
        #pragma unroll
        for (int m = 0; m < 4; m++)
            #pragma unroll
            for (int ks = 0; ks < 2; ks++)
                af[m][ks] = *(const hx8*)&ap[(wm * 64 + m * 16 + l15) * LDH + ks * 32 + g * 8];
        #pragma unroll
        for (int n = 0; n < 4; n++)
            #pragma unroll
            for (int ks = 0; ks < 2; ks++)
                bf[n][ks] = *(const hx8*)&bp[(wn * 64 + n * 16 + l15) * LDH + ks * 32 + g * 8];
        #pragma unroll
        for (int m = 0; m < 4; m++)
            #pragma unroll
            for (int n = 0; n < 4; n++) {
                acc[m][n] = __builtin_amdgcn_mfma_f32_16x16x32_f16(af[m][0], bf[n][0], acc[m][n], 0, 0, 0);
                acc[m][n] = __builtin_amdgcn_mfma_f32_16x16x32_f16(af[m][1], bf[n][1], acc[m][n], 0, 0, 0);
            }
        if (t < 3) {
            #pragma unroll
            for (int it = 0; it < 4; it++) {
                *(uint4*)&As[cur ^ 1][(sr + 32 * it) * LDH + sc * 8] = ga[it];
                *(uint4*)&Bs[cur ^ 1][(sr + 32 * it) * LDH + sc * 8] = gb[it];
            }
        }
        __syncthreads();
        cur ^= 1;
    }

    #pragma unroll
    for (int m = 0; m < 4; m++)
        #pragma unroll
        for (int n = 0; n < 4; n++) {
            int cc = col0 + wn * 64 + n * 16 + l15;
            #pragma unroll
            for (int r = 0; r < 4; r++) {
                int rr = row0 + wm * 64 + m * 16 + g * 4 + r;
                int p = __builtin_amdgcn_cvt_pk_fp8_f32(acc[m][n][r], acc[m][n][r], 0, false);
                Z[(size_t)rr * 256 + cc] = (unsigned char)(p & 0xff);
            }
        }
}

#define ACCP(pw, pm) { \
    fx2f lo_ = __builtin_amdgcn_cvt_pk_f32_fp8(pw, false); \
    fx2f hi_ = __builtin_amdgcn_cvt_pk_f32_fp8(pw, true); \
    acc.x = fmaf(lo_.x, pm, acc.x); acc.y = fmaf(lo_.y, pm, acc.y); \
    acc.z = fmaf(hi_.x, pm, acc.z); acc.w = fmaf(hi_.y, pm, acc.w); }

// agg2 + mean fused: Z fp8 (8 MB -> half the cross-XCD LLC traffic). Wave
// handles 8 consecutive nodes sequentially; per row each lane loads 4 fp8
// (u32) and decodes with v_cvt_pk_f32_fp8 (HW, denormal-correct). Block
// LDS-reduces 4 waves, ONE atomic per lane.
__global__ __launch_bounds__(256) void k_aggm(const unsigned char* __restrict__ Z, const int* __restrict__ indptr,
                                              const int* __restrict__ csrc, const float* __restrict__ dinv,
                                              const float* __restrict__ bias, float* __restrict__ pooled) {
    __shared__ float ps[4][256];
    int tid = threadIdx.x;
    int wid = tid >> 6, lane = tid & 63;
    int n0 = blockIdx.x * 32 + wid * 8;
    fx4 bb = *(const fx4*)&bias[lane * 4];
    fx4 racc = (fx4){0.f, 0.f, 0.f, 0.f};
    #pragma unroll 1
    for (int u = 0; u < 8; u++) {
        int n = n0 + u;
        int beg = indptr[n];
        int cnt8 = indptr[n + 1] - beg;     // multiple of 8 (padded lists)
        float dn = dinv[n];
        const int* cs = csrc + beg;
        fx4 acc = (fx4){0.f, 0.f, 0.f, 0.f};
        for (int i = 0; i < cnt8; i += 8) {
            int4 ia = *(const int4*)&cs[i];
            int4 ib = *(const int4*)&cs[i + 4];
            float m0 = dinv[ia.x] * dn, m1 = dinv[ia.y] * dn;
            float m2 = dinv[ia.z] * dn, m3 = dinv[ia.w] * dn;
            float m4 = dinv[ib.x] * dn, m5 = dinv[ib.y] * dn;
            float m6 = dinv[ib.z] * dn, m7 = dinv[ib.w] * dn;
            unsigned w0 = *(const unsigned*)&Z[(size_t)ia.x * 256 + lane * 4];
            unsigned w1 = *(const unsigned*)&Z[(size_t)ia.y * 256 + lane * 4];
            unsigned w2 = *(const unsigned*)&Z[(size_t)ia.z * 256 + lane * 4];
            unsigned w3 = *(const unsigned*)&Z[(size_t)ia.w * 256 + lane * 4];
            unsigned w4 = *(const unsigned*)&Z[(size_t)ib.x * 256 + lane * 4];
            unsigned w5 = *(const unsigned*)&Z[(size_t)ib.y * 256 + lane * 4];
            unsigned w6 = *(const unsigned*)&Z[(size_t)ib.z * 256 + lane * 4];
            unsigned w7 = *(const unsigned*)&Z[(size_t)ib.w * 256 + lane * 4];
            ACCP(w0, m0)
            ACCP(w1, m1)
            ACCP(w2, m2)
            ACCP(w3, m3)
            ACCP(w4, m4)
            ACCP(w5, m5)
            ACCP(w6, m6)
            ACCP(w7, m7)
        }
        acc += bb;
        racc.x += fmaxf(acc.x, 0.f); racc.y += fmaxf(acc.y, 0.f);
        racc.z += fmaxf(acc.z, 0.f); racc.w += fmaxf(acc.w, 0.f);
    }
    *(fx4*)&ps[wid][lane * 4] = racc;
    __syncthreads();
    float s = ps[0][tid] + ps[1][tid] + ps[2][tid] + ps[3][tid];
    atomicAdd(&pooled[(blockIdx.x >> 4) * 256 + tid], s * (1.f / 512.f));
}

__global__ __launch_bounds__(64) void k_cls(const float* __restrict__ pooled, const float* __restrict__ cw,
                                            const float* __restrict__ cb, float* __restrict__ outp) {
    int b = blockIdx.x, lane = threadIdx.x;
    float po[10];
    #pragma unroll
    for (int o = 0; o < 10; o++) po[o] = 0.f;
    #pragma unroll
    for (int m = 0; m < 4; m++) {
        int hh = lane + m * 64;
        float ph = pooled[b * HID + hh];
        #pragma unroll
        for (int o = 0; o < 10; o++) po[o] = fmaf(ph, cw[hh * 10 + o], po[o]);
    }
    #pragma unroll
    for (int off = 32; off >= 1; off >>= 1) {
        #pragma unroll
        for (int o = 0; o < 10; o++) po[o] += __shfl_down(po[o], off);
    }
    if (lane == 0) {
        #pragma unroll
        for (int o = 0; o < 10; o++) outp[b * 10 + o] = po[o] + cb[o];
    }
}

extern "C" void kernel_launch(void* const* d_in, const int* in_sizes, int n_in,
                              void* d_out, int out_size, void* d_ws, size_t ws_size,
                              hipStream_t stream) {
    const float* x   = (const float*)d_in[0];
    const int*   ei  = (const int*)d_in[1];
    const float* w1  = (const float*)d_in[2];
    const float* b1  = (const float*)d_in[3];
    const float* w2  = (const float*)d_in[4];
    const float* b2  = (const float*)d_in[5];
    const float* g1w = (const float*)d_in[6];
    const float* g1b = (const float*)d_in[7];
    const float* g2w = (const float*)d_in[8];
    const float* g2b = (const float*)d_in[9];
    const float* cw  = (const float*)d_in[10];
    const float* cb  = (const float*)d_in[11];
    float* out = (float*)d_out;
    char* ws = (char*)d_ws;

    _Float16*       H      = (_Float16*)(ws + OFF_H);
    unsigned char*  Z      = (unsigned char*)(ws + OFF_Z);
    float*          h1     = (float*)(ws + OFF_H1);
    _Float16*       xn     = (_Float16*)(ws + OFF_XN);
    float*          y1     = (float*)(ws + OFF_Y1);
    int*            deg    = (int*)(ws + OFF_DEG);
    int*            indptr = (int*)(ws + OFF_INDPTR);
    int*            cnt    = (int*)(ws + OFF_CNT);
    float*          dinv   = (float*)(ws + OFF_DINV);
    int*            csrc   = (int*)(ws + OFF_CSRC);
    float*          wt1    = (float*)(ws + OFF_WT1);
    float*          wt2    = (float*)(ws + OFF_WT2);
    float*          pooled = (float*)(ws + OFF_POOL);
    _Float16*       w2t    = (_Float16*)(ws + OFF_W2T);
    unsigned*       xnz    = (unsigned*)(xn + (size_t)NN * 32);      // dummy row NN of xn
    unsigned*       zz     = (unsigned*)(Z + (size_t)NN * 256);      // dummy row NN of Z (fp8)

    k_setup <<<174, 256, 0, stream>>>(deg, cnt, pooled, w1, w2, wt1, wt2, g2w, w2t, xnz, zz);
    k_c1cnt <<<1024, 256, 0, stream>>>(x, wt1, b1, h1, ei, deg);             // conv1(MFMA) || count
    k_scan  <<<1, 1024, 0, stream>>>(deg, indptr, dinv);
    k_c2fill<<<1344, 256, 0, stream>>>(h1, wt2, b2, xn, ei, deg, indptr, cnt, csrc);  // conv2 || fill(XCD-ranged)
    k_agg32 <<<8192, 256, 0, stream>>>(xn, indptr, csrc, dinv, y1);          // y1 = A^ . X (32-wide)
    k_gemm1 <<<512, 256, 0, stream>>>(y1, g1w, g1b, H);                      // H = fp16(relu(y1@W1+b1))
    k_gemm2m<<<dim3(256, 2), 256, 0, stream>>>(H, w2t, Z);                   // Z = fp8(H@W2)
    k_aggm  <<<1024, 256, 0, stream>>>(Z, indptr, csrc, dinv, g2b, pooled);  // pooled += relu(A^ . Z + b2)/512
    k_cls   <<<64, 64, 0, stream>>>(pooled, cw, cb, out);
}

// Round 16
// 151.930 us; speedup vs baseline: 1.5877x; 1.0113x over previous
//
#include <hip/hip_runtime.h>

#define B_ 64
#define CIN 64
#define T_ 2048
#define C1 16
#define T1 1024
#define C2 32
#define T2 512
#define NN 32768
#define HID 256
#define OUTD 10
#define NE 524288
#define NTOT (NE + NN)          // 557056

typedef __attribute__((ext_vector_type(4))) float fx4;
typedef __attribute__((ext_vector_type(2))) float fx2f;
typedef __attribute__((ext_vector_type(8))) _Float16 hx8;
typedef __attribute__((ext_vector_type(4))) _Float16 hx4;
typedef __attribute__((ext_vector_type(2))) _Float16 hx2;

// ---- workspace byte offsets (ws proven >= 75 MB) ----
#define OFF_H      (0ull)                    // 16 MB: H fp16 [N][256]
#define OFF_Z      (16ull<<20)               // 8 MB + 256B: Z fp8 [N+1][256] (row NN = zero dummy)
#define OFF_H1     (33ull<<20)               // 4 MB: conv1 out
#define OFF_XN     (37ull<<20)               // 2 MB + 64B: xn fp16 [N+1][32] (row NN = zero dummy)
#define OFF_Y1     (42ull<<20)               // 4 MB: agg1 out fp32 [N][32]
#define OFF_DEG    (46ull<<20)               // 128 KB int
#define OFF_INDPTR ((46ull<<20) + (256u<<10))
#define OFF_CNT    ((46ull<<20) + (512u<<10))
#define OFF_DINV   ((46ull<<20) + (768u<<10))   // [N+1] floats
#define OFF_CSRC   (47ull<<20)               // padded CSR src, cap 3.25 MB
#define OFF_WT1    (51ull<<20)               // 20 KB
#define OFF_WT2    (OFF_WT1 + (64u<<10))
#define OFF_POOL   (OFF_WT1 + (128u<<10))
#define OFF_W2T    (OFF_WT1 + (256u<<10))    // 128 KB: W2^T fp16

__device__ __forceinline__ fx4 shfl_xor4(fx4 v, int m) {
    return (fx4){__shfl_xor(v.x, m), __shfl_xor(v.y, m), __shfl_xor(v.z, m), __shfl_xor(v.w, m)};
}

// setup: blocks 0..127 init deg/cnt/pooled (+zero dummy rows of xn, Z);
// 128..143 cvtw (W2->W2T fp16); 144..173 twt (conv weight transpose)
__global__ __launch_bounds__(256) void k_setup(int* deg, int* cnt, float* pooled,
                                               const float* __restrict__ w1, const float* __restrict__ w2,
                                               float* __restrict__ wt1, float* __restrict__ wt2,
                                               const float* __restrict__ gw2, _Float16* __restrict__ w2t,
                                               unsigned* __restrict__ xnz, unsigned* __restrict__ zz) {
    __shared__ float tl[64][65];
    int blk = blockIdx.x, t = threadIdx.x;
    if (blk < 128) {
        int i = blk * 256 + t;
        if (i < NN) { deg[i] = 1; cnt[i] = 0; }   // deg starts at 1 (self-loop)
        if (i < B_ * HID) pooled[i] = 0.f;
        if (blk == 0 && t < 16) xnz[t] = 0u;      // xn dummy row NN (64 B fp16)
        if (blk == 1 && t < 64) zz[t] = 0u;       // Z dummy row NN (256 B fp8)
    } else if (blk < 144) {
        int bb = blk - 128;
        int bx = bb & 3, by = bb >> 2;            // k-tile, n-tile
        #pragma unroll
        for (int it = 0; it < 16; it++) {
            int idx = it * 256 + t;
            int r = idx >> 6, c = idx & 63;
            tl[r][c] = gw2[(size_t)(bx * 64 + r) * 256 + by * 64 + c];
        }
        __syncthreads();
        #pragma unroll
        for (int it = 0; it < 16; it++) {
            int idx = it * 256 + t;
            int r = idx >> 6, c = idx & 63;
            w2t[(size_t)(by * 64 + r) * 256 + bx * 64 + c] = (_Float16)tl[c][r];
        }
    } else {
        int i = (blk - 144) * 256 + t;
        if (i < 16 * 64 * 5) {
            int co = i & 15; int r = i >> 4; int k = r % 5; int ci = r / 5;
            wt1[i] = w1[(co * 64 + ci) * 5 + k];
        }
        int j = i - 16 * 64 * 5;
        if (j >= 0 && j < 32 * 16 * 5) {
            int co = j & 31; int r = j >> 5; int k = r % 5; int ci = r / 5;
            wt2[j] = w2[(co * 16 + ci) * 5 + k];
        }
    }
}

// scan over PADDED degrees ((deg+7)&~7); emits dinv = rsqrt(real deg), dinv[NN]=0.
__global__ __launch_bounds__(1024) void k_scan(const int* __restrict__ deg, int* __restrict__ indptr,
                                               float* __restrict__ dinv) {
    __shared__ int wsum[16];
    int tid = threadIdx.x;
    int lane = tid & 63, w = tid >> 6;
    int base = tid * 32;
    int loc[32]; int s = 0;
    #pragma unroll
    for (int j = 0; j < 32; j++) {
        int d = deg[base + j];
        dinv[base + j] = rsqrtf((float)d);
        loc[j] = d;
        s += (d + 7) & ~7;
    }
    int v = s;                       // inclusive wave scan
    #pragma unroll
    for (int off = 1; off < 64; off <<= 1) {
        int t = __shfl_up(v, off);
        if (lane >= off) v += t;
    }
    if (lane == 63) wsum[w] = v;
    __syncthreads();
    int woff = 0;
    #pragma unroll
    for (int i = 0; i < 16; i++) { int t = wsum[i]; if (i < w) woff += t; }
    int run = woff + v - s;          // exclusive prefix for this thread
    #pragma unroll
    for (int j = 0; j < 32; j++) { indptr[base + j] = run; run += (loc[j] + 7) & ~7; }
    if (tid == 1023) { indptr[NN] = run; dinv[NN] = 0.f; }
}

// FUSED conv1(MFMA implicit GEMM) + count.
#define LDX 72
__global__ __launch_bounds__(256) void k_c1cnt(const float* __restrict__ x, const float* __restrict__ wt1,
                                               const float* __restrict__ b1, float* __restrict__ h1,
                                               const int* __restrict__ ei, int* __restrict__ deg) {
    int blk = blockIdx.x;
    int tid = threadIdx.x;
    if (blk >= 512) {
        int t = (blk - 512) * 256 + tid;   // < NE/4
        int4 d4 = *(const int4*)&ei[NE + 4 * t];
        atomicAdd(&deg[d4.x], 1);
        atomicAdd(&deg[d4.y], 1);
        atomicAdd(&deg[d4.z], 1);
        atomicAdd(&deg[d4.w], 1);
        return;
    }
    __shared__ _Float16 xs[260 * LDX];   // xs[j][ci-swizzled], j = t+2
    __shared__ _Float16 wl[16 * 328];    // wl[co][K], K = kk*64+ci
    __shared__ float ps2[128 * 17];      // pooled out bounce [t1][co]
    int tile = blk & 7;
    int b = blk >> 3;
    int t0 = tile * 256;
    const float* xb = x + ((size_t)b * CIN) * T_ + t0;
    {   // interior cols: lane f covers t 4f..4f+3 of row ci=r -> transposed write
        int f = tid & 63, r0 = tid >> 6;
        #pragma unroll
        for (int it = 0; it < 16; it++) {
            int r = r0 + 4 * it;                       // ci
            fx4 v = *(const fx4*)&xb[(size_t)r * T_ + f * 4];
            #pragma unroll
            for (int q = 0; q < 4; q++) {
                int j = 2 + f * 4 + q;
                xs[j * LDX + ((((r >> 3) ^ (j >> 3)) & 7) << 3) + (r & 7)] = (_Float16)v[q];
            }
        }
        // halo j in {0,1,258,259} (sw(j)=0 there): 1 value per thread
        int r = tid >> 2, c = tid & 3;
        int off = (c < 2) ? (c - 2) : (254 + c);
        int gt = t0 + off;
        float v = 0.f;
        if (gt >= 0 && gt < T_) v = xb[(size_t)r * T_ + off];
        xs[(off + 2) * LDX + r] = (_Float16)v;
        // weights: wl[co][K=kk*64+ci] <- wt1[(ci*5+kk)*16+co]
        for (int i = tid; i < 5120; i += 256) {
            int K = i >> 4, co = i & 15;
            int kk = K >> 6, ci = K & 63;
            wl[co * 328 + K] = (_Float16)wt1[(ci * 5 + kk) * 16 + co];
        }
    }
    __syncthreads();
    int wv = tid >> 6, lane = tid & 63;
    int l15 = lane & 15, g = lane >> 4;
    fx4 acc[4];
    #pragma unroll
    for (int m = 0; m < 4; m++) acc[m] = (fx4){0.f, 0.f, 0.f, 0.f};
    #pragma unroll
    for (int ks = 0; ks < 10; ks++) {
        int kk = ks >> 1;
        int cb = (ks & 1) * 4 + g;                  // ci 8-block index 0..7
        hx8 bf = *(const hx8*)&wl[l15 * 328 + ks * 32 + g * 8];
        #pragma unroll
        for (int m = 0; m < 4; m++) {
            int j = wv * 64 + m * 16 + l15 + kk;    // A row (t + kk), +2-2 folded
            hx8 af = *(const hx8*)&xs[j * LDX + ((((j >> 3) & 7) ^ cb) << 3)];
            acc[m] = __builtin_amdgcn_mfma_f32_16x16x32_f16(af, bf, acc[m], 0, 0, 0);
        }
    }
    // bias + relu + pool2 in-register: C rows g*4+r pair up within the lane
    float bv = b1[l15];
    #pragma unroll
    for (int m = 0; m < 4; m++) {
        int t1b = wv * 32 + m * 8 + g * 2;
        float a0 = fmaxf(acc[m][0] + bv, 0.f);
        float a1 = fmaxf(acc[m][1] + bv, 0.f);
        float a2 = fmaxf(acc[m][2] + bv, 0.f);
        float a3 = fmaxf(acc[m][3] + bv, 0.f);
        ps2[t1b * 17 + l15] = fmaxf(a0, a1);
        ps2[(t1b + 1) * 17 + l15] = fmaxf(a2, a3);
    }
    __syncthreads();
    for (int idx = tid; idx < 2048; idx += 256) {
        int t1 = idx & 127, co = idx >> 7;
        h1[(b * C1 + co) * T1 + tile * 128 + t1] = ps2[t1 * 17 + co];
    }
}

// FUSED conv2 + range-partitioned fill (XCD-affine dest ranges).
__global__ __launch_bounds__(256) void k_c2fill(const float* __restrict__ h1, const float* __restrict__ wt2,
                                                const float* __restrict__ b2, _Float16* __restrict__ xn,
                                                const int* __restrict__ ei, const int* __restrict__ deg,
                                                const int* __restrict__ indptr, int* __restrict__ cnt,
                                                int* __restrict__ csrc) {
    int blk = blockIdx.x;
    int tid = threadIdx.x;
    if (blk >= 256) {
        int j = blk - 256;           // 0..1087
        int g = j & 7, i = j >> 3;   // dest range, edge slice
        int q0 = i * 964;
        int q1 = (q0 + 964 < NE / 4) ? (q0 + 964) : (NE / 4);
        for (int q = q0 + tid; q < q1; q += 256) {
            int4 s4 = *(const int4*)&ei[4 * q];
            int4 d4 = *(const int4*)&ei[NE + 4 * q];
            if ((d4.x >> 12) == g) { int p = indptr[d4.x] + atomicAdd(&cnt[d4.x], 1); csrc[p] = s4.x; }
            if ((d4.y >> 12) == g) { int p = indptr[d4.y] + atomicAdd(&cnt[d4.y], 1); csrc[p] = s4.y; }
            if ((d4.z >> 12) == g) { int p = indptr[d4.z] + atomicAdd(&cnt[d4.z], 1); csrc[p] = s4.z; }
            if ((d4.w >> 12) == g) { int p = indptr[d4.w] + atomicAdd(&cnt[d4.w], 1); csrc[p] = s4.w; }
        }
        // self-loops + pad sentinels for this slice's nodes in range g
        int n0 = i * 241;
        int n1 = (n0 + 241 < NN) ? (n0 + 241) : NN;
        for (int n = n0 + tid; n < n1; n += 256) {
            if ((n >> 12) == g) {
                int base = indptr[n];
                int p = base + atomicAdd(&cnt[n], 1);
                csrc[p] = n;
                int dd = deg[n], dp = (dd + 7) & ~7;
                for (int k = dd; k < dp; k++) csrc[base + k] = NN;
            }
        }
        return;
    }
    __shared__ float xs[16][260];
    __shared__ float ps[128 * 33];
    int tile = blk & 3;
    int b = blk >> 2;
    int t0 = tile * 256;
    float acc[32];
    #pragma unroll
    for (int i = 0; i < 32; i++) acc[i] = 0.f;
    for (int idx = tid; idx < 16 * 260; idx += 256) {
        int r = idx / 260, c = idx % 260;
        int gt = t0 + c - 2;
        float v = 0.f;
        if (gt >= 0 && gt < T1) v = h1[(b * C1 + r) * T1 + gt];
        xs[r][c] = v;
    }
    __syncthreads();
    for (int ci = 0; ci < 16; ci++) {
        float xv[5];
        #pragma unroll
        for (int j = 0; j < 5; j++) xv[j] = xs[ci][tid + j];
        const float* wp = wt2 + (ci * 5) * 32;
        #pragma unroll
        for (int k = 0; k < 5; k++) {
            #pragma unroll
            for (int co = 0; co < 32; co++)
                acc[co] = fmaf(xv[k], wp[k * 32 + co], acc[co]);
        }
    }
    #pragma unroll
    for (int co = 0; co < 32; co++) {
        float a = fmaxf(acc[co] + b2[co], 0.f);
        float o = fmaxf(a, __shfl_xor(a, 1));
        if ((tid & 1) == 0) ps[(tid >> 1) * 33 + co] = o;
    }
    __syncthreads();
    size_t base = ((size_t)b * T2 + tile * 128) * 32;
    for (int idx = tid; idx < 128 * 16; idx += 256) {
        int t1 = idx >> 4, co = (idx & 15) * 2;
        hx2 h;
        h.x = (_Float16)ps[t1 * 33 + co];
        h.y = (_Float16)ps[t1 * 33 + co + 1];
        *(hx2*)&xn[base + t1 * 32 + co] = h;
    }
}

#define ACC4(v, m) \
    acc.x = fmaf((float)v[0], m, acc.x); acc.y = fmaf((float)v[1], m, acc.y); \
    acc.z = fmaf((float)v[2], m, acc.z); acc.w = fmaf((float)v[3], m, acc.w);

// agg1: y1[n,:] = sum_e dinv[s]*dinv[n] * xn[s,:]; xn fp16 (2 MB, L2-resident).
// Wave per node: 8 edge-slots x 8 lanes x hx4, shfl reduce.
__global__ __launch_bounds__(256) void k_agg32(const _Float16* __restrict__ xn, const int* __restrict__ indptr,
                                               const int* __restrict__ csrc, const float* __restrict__ dinv,
                                               float* __restrict__ y1) {
    int lane = threadIdx.x & 63;
    int n = blockIdx.x * 4 + (threadIdx.x >> 6);
    int eg = lane >> 3, fi = lane & 7;
    int beg = indptr[n];
    int cnt8 = indptr[n + 1] - beg;     // multiple of 8
    float dn = dinv[n];
    const int* cs = csrc + beg;
    fx4 acc = (fx4){0.f, 0.f, 0.f, 0.f};
    for (int i = 0; i < cnt8; i += 8) {
        int s = cs[i + eg];
        float m = dinv[s] * dn;
        hx4 v = *(const hx4*)&xn[(size_t)s * 32 + fi * 4];
        ACC4(v, m)
    }
    acc += shfl_xor4(acc, 8);
    acc += shfl_xor4(acc, 16);
    acc += shfl_xor4(acc, 32);
    if (lane < 8) *(fx4*)&y1[(size_t)n * 32 + fi * 4] = acc;
}

// gemm1: H[N,256] = fp16( relu(y1[N,32] @ W1[32,256] + b1) ); 64-row tiles.
__global__ __launch_bounds__(256) void k_gemm1(const float* __restrict__ A, const float* __restrict__ W,
                                               const float* __restrict__ bias, _Float16* __restrict__ H) {
    __shared__ __align__(16) float xT[32 * 68];   // [k][r], 64 rows + pad
    __shared__ __align__(16) float wl[32 * 256];
    int tid = threadIdx.x;
    int ty = tid >> 4, tx = tid & 15;
    int rows0 = blockIdx.x * 64;
    int kq = tid & 7, rs = tid >> 3;              // staging coords (rs 0..31)
    {
        fx4 v0 = *(const fx4*)&A[(size_t)(rows0 + rs) * 32 + kq * 4];
        fx4 v1 = *(const fx4*)&A[(size_t)(rows0 + rs + 32) * 32 + kq * 4];
        #pragma unroll
        for (int i = 0; i < 4; i++) {
            xT[(kq * 4 + i) * 68 + rs]      = v0[i];
            xT[(kq * 4 + i) * 68 + rs + 32] = v1[i];
        }
    }
    #pragma unroll
    for (int m = 0; m < 8; m++)
        *(fx4*)&wl[m * 1024 + tid * 4] = *(const fx4*)&W[(size_t)(m * 1024 + tid * 4)];
    __syncthreads();

    fx4 c[4][4];
    #pragma unroll
    for (int i = 0; i < 4; i++)
        #pragma unroll
        for (int j = 0; j < 4; j++) c[i][j] = (fx4){0.f, 0.f, 0.f, 0.f};

    #pragma unroll 8
    for (int kk = 0; kk < 32; kk++) {
        fx4 xa = *(const fx4*)&xT[kk * 68 + ty * 4];
        fx4 w[4];
        w[0] = *(const fx4*)&wl[kk * 256 + tx * 8];
        w[1] = *(const fx4*)&wl[kk * 256 + tx * 8 + 4];
        w[2] = *(const fx4*)&wl[kk * 256 + tx * 8 + 128];
        w[3] = *(const fx4*)&wl[kk * 256 + tx * 8 + 132];
        #pragma unroll
        for (int j = 0; j < 4; j++) {
            c[0][j] += xa.x * w[j];
            c[1][j] += xa.y * w[j];
            c[2][j] += xa.z * w[j];
            c[3][j] += xa.w * w[j];
        }
    }
    fx4 bb[4];
    bb[0] = *(const fx4*)&bias[tx * 8];
    bb[1] = *(const fx4*)&bias[tx * 8 + 4];
    bb[2] = *(const fx4*)&bias[tx * 8 + 128];
    bb[3] = *(const fx4*)&bias[tx * 8 + 132];
    #pragma unroll
    for (int i = 0; i < 4; i++) {
        int r = rows0 + ty * 4 + i;
        fx4 v0 = c[i][0] + bb[0], v1 = c[i][1] + bb[1];
        fx4 v2 = c[i][2] + bb[2], v3 = c[i][3] + bb[3];
        hx8 h0, h1;
        #pragma unroll
        for (int q = 0; q < 4; q++) {
            h0[q]     = (_Float16)fmaxf(v0[q], 0.f);
            h0[q + 4] = (_Float16)fmaxf(v1[q], 0.f);
            h1[q]     = (_Float16)fmaxf(v2[q], 0.f);
            h1[q + 4] = (_Float16)fmaxf(v3[q], 0.f);
        }
        *(hx8*)&H[(size_t)r * 256 + tx * 8]       = h0;
        *(hx8*)&H[(size_t)r * 256 + tx * 8 + 128] = h1;
    }
}

// gemm2 MFMA: Z[N,256] = fp8( H[N,256] @ W2 ), 128x128 tile, BK=64, dbuf LDS.
#define LDH 72
__global__ __launch_bounds__(256, 2) void k_gemm2m(const _Float16* __restrict__ A,
                                                   const _Float16* __restrict__ Bt,
                                                   unsigned char* __restrict__ Z) {
    __shared__ __align__(16) _Float16 As[2][128 * LDH];
    __shared__ __align__(16) _Float16 Bs[2][128 * LDH];
    int tid = threadIdx.x;
    int lane = tid & 63, wid = tid >> 6;
    int wm = wid >> 1, wn = wid & 1;
    int row0 = blockIdx.x * 128, col0 = blockIdx.y * 128;
    int l15 = lane & 15, g = lane >> 4;
    int sr = tid >> 3, sc = tid & 7;

    fx4 acc[4][4];
    #pragma unroll
    for (int m = 0; m < 4; m++)
        #pragma unroll
        for (int n = 0; n < 4; n++) acc[m][n] = (fx4){0.f, 0.f, 0.f, 0.f};

    uint4 ga[4], gb[4];
    #pragma unroll
    for (int it = 0; it < 4; it++) {
        ga[it] = *(const uint4*)&A[(size_t)(row0 + sr + 32 * it) * 256 + sc * 8];
        gb[it] = *(const uint4*)&Bt[(size_t)(col0 + sr + 32 * it) * 256 + sc * 8];
    }
    #pragma unroll
    for (int it = 0; it < 4; it++) {
        *(uint4*)&As[0][(sr + 32 * it) * LDH + sc * 8] = ga[it];
        *(uint4*)&Bs[0][(sr + 32 * it) * LDH + sc * 8] = gb[it];
    }
    __syncthreads();

    int cur = 0;
    for (int t = 0; t < 4; t++) {
        if (t < 3) {
            int k0 = (t + 1) * 64;
            #pragma unroll
            for (int it = 0; it < 4; it++) {
                ga[it] = *(const uint4*)&A[(size_t)(row0 + sr + 32 * it) * 256 + k0 + sc * 8];
                gb[it] = *(const uint4*)&Bt[(size_t)(col0 + sr + 32 * it) * 256 + k0 + sc * 8];
            }
        }
        const _Float16* ap = As[cur];
        const _Float16* bp = Bs[cur];
        hx8 af[4][2], bf[4][2];
        #pragma unroll
        for (int m = 0; m < 4; m++)
            #pragma unroll
            for (int ks = 0; ks < 2; ks++)
                af[m][ks] = *(const hx8*)&ap[(wm * 64 + m * 16 + l15) * LDH + ks * 32 + g * 8];
        #pragma unroll
        for (int n = 0; n < 4; n++)
            #pragma unroll
            for (int ks = 0; ks < 2; ks++)
                bf[n][ks] = *(const hx8*)&bp[(wn * 64 + n * 16 + l15) * LDH + ks * 32 + g * 8];
        #pragma unroll
        for (int m = 0; m < 4; m++)
            #pragma unroll
            for (int n = 0; n < 4; n++) {
                acc[m][n] = __builtin_amdgcn_mfma_f32_16x16x32_f16(af[m][0], bf[n][0], acc[m][n], 0, 0, 0);
                acc[m][n] = __builtin_amdgcn_mfma_f32_16x16x32_f16(af[m][1], bf[n][1], acc[m][n], 0, 0, 0);
            }
        if (t < 3) {
            #pragma unroll
            for (int it = 0; it < 4; it++) {
                *(uint4*)&As[cur ^ 1][(sr + 32 * it) * LDH + sc * 8] = ga[it];
                *(uint4*)&Bs[cur ^ 1][(sr + 32 * it) * LDH + sc * 8] = gb[it];
            }
        }
        __syncthreads();
        cur ^= 1;
    }

    #pragma unroll
    for (int m = 0; m < 4; m++)
        #pragma unroll
        for (int n = 0; n < 4; n++) {
            int cc = col0 + wn * 64 + n * 16 + l15;
            #pragma unroll
            for (int r = 0; r < 4; r++) {
                int rr = row0 + wm * 64 + m * 16 + g * 4 + r;
                int p = __builtin_amdgcn_cvt_pk_fp8_f32(acc[m][n][r], acc[m][n][r], 0, false);
                Z[(size_t)rr * 256 + cc] = (unsigned char)(p & 0xff);
            }
        }
}

#define ACCP(pw, pm) { \
    fx2f lo_ = __builtin_amdgcn_cvt_pk_f32_fp8(pw, false); \
    fx2f hi_ = __builtin_amdgcn_cvt_pk_f32_fp8(pw, true); \
    acc.x = fmaf(lo_.x, pm, acc.x); acc.y = fmaf(lo_.y, pm, acc.y); \
    acc.z = fmaf(hi_.x, pm, acc.z); acc.w = fmaf(hi_.y, pm, acc.w); }

// agg2 + mean, 2-WAY FEATURE-SLICED for per-XCD L2 residency: slice =
// blockIdx&1 (128 features, 4 MB stripe of fp8 Z -> fits one XCD's 4 MB L2;
// even blocks -> even XCDs under round-robin). Half-wave per row (32 lanes x
// u32 = 128 fp8); 8 edges in flight per iter (4 per half); 8 nodes
// sequential per wave; block LDS-combines 4 waves; 1 atomic per feature.
__global__ __launch_bounds__(256) void k_aggm(const unsigned char* __restrict__ Z, const int* __restrict__ indptr,
                                              const int* __restrict__ csrc, const float* __restrict__ dinv,
                                              const float* __restrict__ bias, float* __restrict__ pooled) {
    __shared__ float ps[4][128];
    int tid = threadIdx.x;
    int wid = tid >> 6, lane = tid & 63;
    int slice = blockIdx.x & 1;
    int grp = blockIdx.x >> 1;           // 0..1023, 32 nodes each
    int h = lane >> 5, fl = lane & 31;   // half-wave, feature-quad
    int fb = slice * 128 + fl * 4;       // feature base
    fx4 bb = *(const fx4*)&bias[fb];
    fx4 racc = (fx4){0.f, 0.f, 0.f, 0.f};
    int n0 = grp * 32 + wid * 8;
    #pragma unroll 1
    for (int u = 0; u < 8; u++) {
        int n = n0 + u;
        int beg = indptr[n];
        int cnt8 = indptr[n + 1] - beg;  // multiple of 8 (padded lists)
        float dn = dinv[n];
        const int* cs = csrc + beg;
        fx4 acc = (fx4){0.f, 0.f, 0.f, 0.f};
        for (int i = 0; i < cnt8; i += 8) {
            int4 ia = *(const int4*)&cs[i];
            int4 ib = *(const int4*)&cs[i + 4];
            int e0 = h ? ia.y : ia.x;
            int e1 = h ? ia.w : ia.z;
            int e2 = h ? ib.y : ib.x;
            int e3 = h ? ib.w : ib.z;
            float m0 = dinv[e0] * dn, m1 = dinv[e1] * dn;
            float m2 = dinv[e2] * dn, m3 = dinv[e3] * dn;
            unsigned w0 = *(const unsigned*)&Z[(size_t)e0 * 256 + fb];
            unsigned w1 = *(const unsigned*)&Z[(size_t)e1 * 256 + fb];
            unsigned w2 = *(const unsigned*)&Z[(size_t)e2 * 256 + fb];
            unsigned w3 = *(const unsigned*)&Z[(size_t)e3 * 256 + fb];
            ACCP(w0, m0)
            ACCP(w1, m1)
            ACCP(w2, m2)
            ACCP(w3, m3)
        }
        acc += shfl_xor4(acc, 32);       // combine two half-wave edge sets
        acc += bb;
        racc.x += fmaxf(acc.x, 0.f); racc.y += fmaxf(acc.y, 0.f);
        racc.z += fmaxf(acc.z, 0.f); racc.w += fmaxf(acc.w, 0.f);
    }
    if (h == 0) *(fx4*)&ps[wid][fl * 4] = racc;
    __syncthreads();
    if (tid < 128) {
        float s = ps[0][tid] + ps[1][tid] + ps[2][tid] + ps[3][tid];
        atomicAdd(&pooled[(grp >> 4) * 256 + slice * 128 + tid], s * (1.f / 512.f));
    }
}

__global__ __launch_bounds__(64) void k_cls(const float* __restrict__ pooled, const float* __restrict__ cw,
                                            const float* __restrict__ cb, float* __restrict__ outp) {
    int b = blockIdx.x, lane = threadIdx.x;
    float po[10];
    #pragma unroll
    for (int o = 0; o < 10; o++) po[o] = 0.f;
    #pragma unroll
    for (int m = 0; m < 4; m++) {
        int hh = lane + m * 64;
        float ph = pooled[b * HID + hh];
        #pragma unroll
        for (int o = 0; o < 10; o++) po[o] = fmaf(ph, cw[hh * 10 + o], po[o]);
    }
    #pragma unroll
    for (int off = 32; off >= 1; off >>= 1) {
        #pragma unroll
        for (int o = 0; o < 10; o++) po[o] += __shfl_down(po[o], off);
    }
    if (lane == 0) {
        #pragma unroll
        for (int o = 0; o < 10; o++) outp[b * 10 + o] = po[o] + cb[o];
    }
}

extern "C" void kernel_launch(void* const* d_in, const int* in_sizes, int n_in,
                              void* d_out, int out_size, void* d_ws, size_t ws_size,
                              hipStream_t stream) {
    const float* x   = (const float*)d_in[0];
    const int*   ei  = (const int*)d_in[1];
    const float* w1  = (const float*)d_in[2];
    const float* b1  = (const float*)d_in[3];
    const float* w2  = (const float*)d_in[4];
    const float* b2  = (const float*)d_in[5];
    const float* g1w = (const float*)d_in[6];
    const float* g1b = (const float*)d_in[7];
    const float* g2w = (const float*)d_in[8];
    const float* g2b = (const float*)d_in[9];
    const float* cw  = (const float*)d_in[10];
    const float* cb  = (const float*)d_in[11];
    float* out = (float*)d_out;
    char* ws = (char*)d_ws;

    _Float16*       H      = (_Float16*)(ws + OFF_H);
    unsigned char*  Z      = (unsigned char*)(ws + OFF_Z);
    float*          h1     = (float*)(ws + OFF_H1);
    _Float16*       xn     = (_Float16*)(ws + OFF_XN);
    float*          y1     = (float*)(ws + OFF_Y1);
    int*            deg    = (int*)(ws + OFF_DEG);
    int*            indptr = (int*)(ws + OFF_INDPTR);
    int*            cnt    = (int*)(ws + OFF_CNT);
    float*          dinv   = (float*)(ws + OFF_DINV);
    int*            csrc   = (int*)(ws + OFF_CSRC);
    float*          wt1    = (float*)(ws + OFF_WT1);
    float*          wt2    = (float*)(ws + OFF_WT2);
    float*          pooled = (float*)(ws + OFF_POOL);
    _Float16*       w2t    = (_Float16*)(ws + OFF_W2T);
    unsigned*       xnz    = (unsigned*)(xn + (size_t)NN * 32);      // dummy row NN of xn
    unsigned*       zz     = (unsigned*)(Z + (size_t)NN * 256);      // dummy row NN of Z (fp8)

    k_setup <<<174, 256, 0, stream>>>(deg, cnt, pooled, w1, w2, wt1, wt2, g2w, w2t, xnz, zz);
    k_c1cnt <<<1024, 256, 0, stream>>>(x, wt1, b1, h1, ei, deg);             // conv1(MFMA) || count
    k_scan  <<<1, 1024, 0, stream>>>(deg, indptr, dinv);
    k_c2fill<<<1344, 256, 0, stream>>>(h1, wt2, b2, xn, ei, deg, indptr, cnt, csrc);  // conv2 || fill(XCD-ranged)
    k_agg32 <<<8192, 256, 0, stream>>>(xn, indptr, csrc, dinv, y1);          // y1 = A^ . X (32-wide)
    k_gemm1 <<<512, 256, 0, stream>>>(y1, g1w, g1b, H);                      // H = fp16(relu(y1@W1+b1))
    k_gemm2m<<<dim3(256, 2), 256, 0, stream>>>(H, w2t, Z);                   // Z = fp8(H@W2)
    k_aggm  <<<2048, 256, 0, stream>>>(Z, indptr, csrc, dinv, g2b, pooled);  // pooled += relu(A^ . Z + b2)/512 (2-sliced)
    k_cls   <<<64, 64, 0, stream>>>(pooled, cw, cb, out);
}